// Round 19
// baseline (623.473 us; speedup 1.0000x reference)
//
#include <hip/hip_runtime.h>
#include <hip/hip_fp16.h>
#include <hip/hip_fp8.h>
#include <math.h>
#include <type_traits>

#define N_NODES 50000
#define E_EDGES 1600000
#define TAU     0.5f
#define BN_EPS  1e-5f
#define SBSH    9                        // 512 dst nodes per super-bucket
#define NSB     ((N_NODES + 511) >> 9)   // 98 super-buckets
#define NSUBL   8                        // staging sub-lists (spread cursor LINES)
#define SUBCAP  2560                     // entries per sub-list (mean 2048 + >10 sigma)
#define BINCAP  48                       // LDS bin capacity (mean 10.4, +11 sigma)
#define EPB     1024                     // edges per scatter block
#define SCGRID  ((E_EDGES + EPB - 1) / EPB)
#define BSTR    16                       // cursor stride in ints (64B/line)

typedef _Float16 f16x8 __attribute__((ext_vector_type(8)));
typedef float    f32x4 __attribute__((ext_vector_type(4)));

__device__ __forceinline__ float dot8h(int4 a, int4 b) {
  const __half2* ah = (const __half2*)&a;
  const __half2* bh = (const __half2*)&b;
  float acc = 0.0f;
  #pragma unroll
  for (int q = 0; q < 4; ++q) {
    float2 fa = __half22float2(ah[q]);
    float2 fb = __half22float2(bh[q]);
    acc = fmaf(fa.x, fb.x, acc);
    acc = fmaf(fa.y, fb.y, acc);
  }
  return acc;
}

// ---------------------------------------------------------------------------
// 1) normalized fp16 features
__global__ __launch_bounds__(256) void xn_norm(
    const float* __restrict__ x, __half* __restrict__ xn, int n) {
  int wid  = (int)((blockIdx.x * blockDim.x + threadIdx.x) >> 6);
  int lane = threadIdx.x & 63;
  if (wid >= n) return;
  float2 v = ((const float2*)(x + (size_t)wid * 128))[lane];
  float s = v.x * v.x + v.y * v.y;
  #pragma unroll
  for (int off = 32; off; off >>= 1) s += __shfl_xor(s, off);
  float inv = 1.0f / (sqrtf(s) + 1e-12f);
  ((__half2*)(xn + (size_t)wid * 128))[lane] =
      __floats2half2_rn(v.x * inv, v.y * inv);
}

// ---------------------------------------------------------------------------
// 2a) LDS-binned scatter (unchanged)
__global__ __launch_bounds__(256) void scatter_sb(
    const int* __restrict__ src, const int* __restrict__ dst,
    int* __restrict__ gc, unsigned* __restrict__ staging,
    int* __restrict__ ocnt, unsigned* __restrict__ ostage, int e) {
  __shared__ unsigned bins[NSB][BINCAP];
  __shared__ int bcount[NSB];
  const int tid  = threadIdx.x;
  const int wv   = tid >> 6;
  const int lane = tid & 63;
  const int sl   = blockIdx.x & (NSUBL - 1);
  for (int i = tid; i < NSB; i += 256) bcount[i] = 0;
  __syncthreads();

  int base = blockIdx.x * EPB;
  int bend = min(base + EPB, e);
  for (int i = base + tid; i < bend; i += 256) {
    int d = dst[i], s = src[i];
    int sb = d >> SBSH;
    int pos = atomicAdd(&bcount[sb], 1);
    if (pos < BINCAP) {
      bins[sb][pos] = (unsigned)s | ((unsigned)(d & 511) << 16);
    } else {
      int op = atomicAdd(ocnt, 1);
      ostage[op] = (unsigned)s | ((unsigned)d << 16);   // full dst
    }
  }
  __syncthreads();

  for (int sb = wv; sb < NSB; sb += 4) {
    int cnt = min(bcount[sb], BINCAP);
    if (cnt > 0) {
      int cell = sb * NSUBL + sl;
      int gbase = 0;
      if (lane == 0) gbase = atomicAdd(&gc[cell * BSTR], cnt);
      gbase = __shfl(gbase, 0);
      if (gbase + cnt <= SUBCAP) {
        if (lane < cnt)
          staging[(size_t)cell * SUBCAP + gbase + lane] = bins[sb][lane];
      } else if (lane < cnt) {
        unsigned u = bins[sb][lane];
        int op = atomicAdd(ocnt, 1);
        ostage[op] = (u & 0xFFFFu) | ((unsigned)((sb << SBSH) | (u >> 16)) << 16);
      }
    }
  }
}

// ---------------------------------------------------------------------------
// 2b) per-SB LDS histogram over the 8 sub-lists -> deg + SB total
__global__ __launch_bounds__(256) void hist_sb(
    const unsigned* __restrict__ staging, const int* __restrict__ gc,
    int* __restrict__ deg, int* __restrict__ sbsum, int n) {
  __shared__ int h[512];
  __shared__ int wt[4];
  int sb = blockIdx.x;
  for (int i = threadIdx.x; i < 512; i += 256) h[i] = 0;
  __syncthreads();
  for (int s = 0; s < NSUBL; ++s) {
    int cell = sb * NSUBL + s;
    int m = min(gc[cell * BSTR], SUBCAP);
    for (int i = threadIdx.x; i < m; i += 256)
      atomicAdd(&h[(staging[(size_t)cell * SUBCAP + i] >> 16) & 511], 1);
  }
  __syncthreads();
  int d0 = sb << SBSH;
  for (int i = threadIdx.x; i < 512; i += 256)
    if (d0 + i < n) deg[d0 + i] = h[i];
  int t = h[threadIdx.x] + h[threadIdx.x + 256];
  #pragma unroll
  for (int off = 32; off; off >>= 1) t += __shfl_xor(t, off);
  if ((threadIdx.x & 63) == 0) wt[threadIdx.x >> 6] = t;
  __syncthreads();
  if (threadIdx.x == 0) sbsum[sb] = wt[0] + wt[1] + wt[2] + wt[3];
}

// ---------------------------------------------------------------------------
// 2b') overflow patch (no-op when ocnt==0)
__global__ __launch_bounds__(256) void overflow_deg(
    const unsigned* __restrict__ ostage, const int* __restrict__ ocnt,
    int* __restrict__ deg, int* __restrict__ sbsum) {
  int m = *ocnt;
  for (int i = blockIdx.x * blockDim.x + threadIdx.x; i < m;
       i += gridDim.x * blockDim.x) {
    int d = (int)(ostage[i] >> 16);
    atomicAdd(&deg[d], 1);
    atomicAdd(&sbsum[d >> SBSH], 1);
  }
}

// ---------------------------------------------------------------------------
// 3a) exclusive scan over the 98 SB sums
__global__ void scan_sb(const int* __restrict__ sbsum, int* __restrict__ sbbase,
                        int* __restrict__ rowptr, int n) {
  __shared__ int part[128];
  int t = (int)threadIdx.x;
  int v = (t < NSB) ? sbsum[t] : 0;
  part[t] = v;
  __syncthreads();
  for (int off = 1; off < 128; off <<= 1) {
    int u = (t >= off) ? part[t - off] : 0;
    __syncthreads();
    part[t] += u;
    __syncthreads();
  }
  if (t < NSB) sbbase[t] = part[t] - v;
  if (t == 127) rowptr[n] = part[127];
}

// ---------------------------------------------------------------------------
// 3b) rowptr within SB: 512-element block scan (2 per thread)
__global__ __launch_bounds__(256) void rowptr_sb(
    const int* __restrict__ deg, const int* __restrict__ sbbase,
    int* __restrict__ rowptr, int n) {
  __shared__ int part[256];
  int sb = blockIdx.x;
  int d0 = sb << SBSH;
  int t = (int)threadIdx.x;
  int e0 = d0 + 2 * t;
  int v0 = (e0 < n) ? deg[e0] : 0;
  int v1 = (e0 + 1 < n) ? deg[e0 + 1] : 0;
  int s = v0 + v1;
  part[t] = s;
  __syncthreads();
  for (int off = 1; off < 256; off <<= 1) {
    int u = (t >= off) ? part[t - off] : 0;
    __syncthreads();
    part[t] += u;
    __syncthreads();
  }
  int ex = part[t] - s + sbbase[sb];
  if (e0 < n) rowptr[e0] = ex;
  if (e0 + 1 < n) rowptr[e0 + 1] = ex + v0;
}

// ---------------------------------------------------------------------------
// 2c) placement (unchanged)
__global__ __launch_bounds__(256) void place_sb(
    const unsigned* __restrict__ staging, const int* __restrict__ gc,
    const int* __restrict__ rowptr, unsigned short* __restrict__ csr16,
    int* __restrict__ gcur, int n) {
  __shared__ int cur[512];
  int sb = blockIdx.x;
  int d0 = sb << SBSH;
  for (int i = threadIdx.x; i < 512; i += 256)
    cur[i] = (d0 + i < n) ? rowptr[d0 + i] : 0;
  __syncthreads();
  for (int s = 0; s < NSUBL; ++s) {
    int cell = sb * NSUBL + s;
    int m = min(gc[cell * BSTR], SUBCAP);
    for (int i = threadIdx.x; i < m; i += 256) {
      unsigned u = staging[(size_t)cell * SUBCAP + i];
      int j = (u >> 16) & 511;
      int pos = atomicAdd(&cur[j], 1);
      csr16[pos] = (unsigned short)(u & 0xFFFFu);
    }
  }
  __syncthreads();
  for (int i = threadIdx.x; i < 512; i += 256)
    if (d0 + i < n) gcur[d0 + i] = cur[i];
}

// ---------------------------------------------------------------------------
// 2c') overflow placement (no-op when ocnt==0)
__global__ __launch_bounds__(256) void overflow_place(
    const unsigned* __restrict__ ostage, const int* __restrict__ ocnt,
    int* __restrict__ gcur, unsigned short* __restrict__ csr16) {
  int m = *ocnt;
  for (int i = blockIdx.x * blockDim.x + threadIdx.x; i < m;
       i += gridDim.x * blockDim.x) {
    unsigned u = ostage[i];
    int d = (int)(u >> 16);
    int pos = atomicAdd(&gcur[d], 1);
    csr16[pos] = (unsigned short)(u & 0xFFFFu);
  }
}

// ---------------------------------------------------------------------------
// 4) edge weights, dst-ordered (unchanged)
__global__ __launch_bounds__(256) void edge_weights(
    const __half* __restrict__ xn, const int* __restrict__ rowptr,
    const unsigned short* __restrict__ csr_src16,
    unsigned* __restrict__ csrp, float* __restrict__ denom, int n) {
  int wid  = (int)((blockIdx.x * blockDim.x + threadIdx.x) >> 6);
  int lane = threadIdx.x & 63;
  if (wid >= n) return;
  int grp = lane >> 3;       // edge slot 0..7
  int sub = lane & 7;        // 16-dim slice
  int beg = rowptr[wid], end = rowptr[wid + 1];
  const int4* xdp = (const int4*)(xn + (size_t)wid * 128);
  int4 xd0 = xdp[sub], xd1 = xdp[sub + 8];
  float wsum = 0.0f;

  for (int base = beg; base < end; base += 64) {
    int m = min(64, end - base);
    int sv = (lane < m) ? (int)csr_src16[base + lane] : 0;
    int iters = (m + 7) >> 3;
    #pragma unroll 2
    for (int q = 0; q < iters; ++q) {
      int ei = q * 8 + grp;
      int s = __shfl(sv, ei);
      const int4* xsp = (const int4*)(xn + (size_t)s * 128);
      int4 xs0 = xsp[sub], xs1 = xsp[sub + 8];
      float dp = dot8h(xs0, xd0) + dot8h(xs1, xd1);
      dp += __shfl_xor(dp, 1);
      dp += __shfl_xor(dp, 2);
      dp += __shfl_xor(dp, 4);
      bool valid = ei < m;
      float w = valid ? __expf(dp * (1.0f / TAU)) : 0.0f;
      wsum += w;
      if (valid && sub == 0) {
        unsigned w16 = (unsigned)__half_as_ushort(__float2half_rn(w));
        csrp[base + ei] = (unsigned)s | (w16 << 16);
      }
    }
  }
  wsum += __shfl_xor(wsum, 8);
  wsum += __shfl_xor(wsum, 16);
  wsum += __shfl_xor(wsum, 32);
  if (lane == 0) denom[wid] = wsum;
}

// ---------------------------------------------------------------------------
// 5a) weight prepack in MFMA fragment order (unchanged)
__global__ __launch_bounds__(256) void prep_weights(
    const float* __restrict__ Wn0, const float* __restrict__ Wr0,
    const float* __restrict__ Wn1, const float* __restrict__ Wr1,
    const float* __restrict__ Wn2, const float* __restrict__ Wr2,
    const float* __restrict__ cn0, const float* __restrict__ cr0,
    const float* __restrict__ cn1, const float* __restrict__ cr1,
    const float* __restrict__ cn2, const float* __restrict__ cr2,
    __half* __restrict__ WtN0, __half* __restrict__ WtR0,
    __half* __restrict__ WtN1, __half* __restrict__ WtR1,
    __half* __restrict__ WtN2, __half* __restrict__ WtR2,
    float* __restrict__ bias0, float* __restrict__ bias1,
    float* __restrict__ bias2) {
  int i = blockIdx.x * blockDim.x + threadIdx.x;
  const float* Ws[6] = {Wn0, Wr0, Wn1, Wr1, Wn2, Wr2};
  __half*     Wts[6] = {WtN0, WtR0, WtN1, WtR1, WtN2, WtR2};
  int seg = -1, off = 0;
  if (i < 65536)        { seg = i >> 14;               off = i & 16383; }
  else if (i < 81920)   { int j = i - 65536; seg = 4 + (j >> 13); off = j & 8191; }
  if (seg >= 0) {
    int DO = (seg < 4) ? 128 : 64;
    int c = off >> 7, k = off & 127;
    int t = c >> 4, kc = k >> 5, kgrp = (k >> 3) & 3, j = k & 7;
    int lane = (c & 15) | (kgrp << 4);
    int idx = (((t * 4 + kc) * 64 + lane) << 3) + j;
    Wts[seg][idx] = __float2half_rn(Ws[seg][(size_t)k * DO + c]);
  }
  if (i < 128) { bias0[i] = cn0[i] + cr0[i]; bias1[i] = cn1[i] + cr1[i]; }
  if (i < 64)  { bias2[i] = cn2[i] + cr2[i]; }
}

// ---------------------------------------------------------------------------
// 5b) dual MFMA GEMM (unchanged from R18)
template <int DO, typename TIN, int YMODE>
__global__ __launch_bounds__(256) void gemm_dual_mfma(
    const TIN* __restrict__ H, const __half* __restrict__ WfN,
    const __half* __restrict__ WfR, const float* __restrict__ bias,
    void* __restrict__ Yv, __half* __restrict__ Z, int n) {
  constexpr int NT = DO / 16;
  const int lane  = threadIdx.x & 63;
  const int w     = threadIdx.x >> 6;
  const int row0  = blockIdx.x * 64 + w * 16;
  const int col16 = lane & 15;
  const int kgrp  = (lane >> 4) * 8;
  const size_t arow = (size_t)min(row0 + col16, n - 1);

  f32x4 acc[2][NT];
  #pragma unroll
  for (int m = 0; m < 2; ++m)
    #pragma unroll
    for (int t = 0; t < NT; ++t) acc[m][t] = (f32x4){0.f, 0.f, 0.f, 0.f};

  #pragma unroll
  for (int kc = 0; kc < 4; ++kc) {
    f16x8 a;
    if constexpr (std::is_same<TIN, float>::value) {
      const float* hp = H + arow * 128 + kc * 32 + kgrp;
      float4 f0 = *(const float4*)hp;
      float4 f1 = *(const float4*)(hp + 4);
      a[0] = (_Float16)f0.x; a[1] = (_Float16)f0.y;
      a[2] = (_Float16)f0.z; a[3] = (_Float16)f0.w;
      a[4] = (_Float16)f1.x; a[5] = (_Float16)f1.y;
      a[6] = (_Float16)f1.z; a[7] = (_Float16)f1.w;
    } else {
      a = *(const f16x8*)(H + arow * 128 + kc * 32 + kgrp);
    }
    const f16x8* bN = (const f16x8*)(WfN + ((size_t)(kc * 64 + lane) << 3));
    const f16x8* bR = (const f16x8*)(WfR + ((size_t)(kc * 64 + lane) << 3));
    #pragma unroll
    for (int t = 0; t < NT; ++t) {
      f16x8 b = bN[t * 256];
      acc[0][t] = __builtin_amdgcn_mfma_f32_16x16x32_f16(a, b, acc[0][t], 0, 0, 0);
    }
    #pragma unroll
    for (int t = 0; t < NT; ++t) {
      f16x8 b = bR[t * 256];
      acc[1][t] = __builtin_amdgcn_mfma_f32_16x16x32_f16(a, b, acc[1][t], 0, 0, 0);
    }
  }

  const int rbase = (lane >> 4) * 4;
  #pragma unroll
  for (int t = 0; t < NT; ++t) {
    int col = t * 16 + col16;
    float bz = bias[col];
    #pragma unroll
    for (int j = 0; j < 4; ++j) {
      int row = row0 + rbase + j;
      if (row < n) {
        if constexpr (YMODE == 1) {
          int pidx = col >> 6, incol = col & 63;
          __hip_fp8_e4m3 q(acc[0][t][j]);
          ((unsigned char*)Yv)[((size_t)pidx * n + row) * 64 + incol] = q.__x;
        } else {
          int pidx = col >> 5, incol = col & 31;
          ((__half*)Yv)[((size_t)pidx * n + row) * 32 + incol] =
              __float2half_rn(acc[0][t][j]);
        }
        Z[(size_t)row * DO + col] = __float2half_rn(acc[1][t][j] + bz);
      }
    }
  }
}

// ---------------------------------------------------------------------------
// 6) aggregation, CHANNEL-OWNED lanes (no cross-lane reduce):
// FP8Y: lane owns channel `lane` of a 64-ch fp8 plane. Per edge the whole
// wave does ONE coalesced 64B line read (1 request vs 4), 1 cvt_f32_fp8,
// 1 fma into a private accumulator. fp16 final: 2 edges in flight
// (grp=lane>>5, ch=lane&31), one shfl_xor(32) combine.
template <bool DO_BN, bool HALF_OUT, bool FP8Y>
__global__ __launch_bounds__(256) void agg_pass(
    const void* __restrict__ Ypv, const __half* __restrict__ Zb,
    const int* __restrict__ rowptr, const unsigned* __restrict__ csrp,
    const float* __restrict__ denom,
    const float* __restrict__ g, const float* __restrict__ bb,
    const float* __restrict__ mm, const float* __restrict__ vv,
    void* __restrict__ outv, int dofull, int choff, int n) {
  int wid  = (int)((blockIdx.x * blockDim.x + threadIdx.x) >> 6);
  int lane = threadIdx.x & 63;
  if (wid >= n) return;
  int beg = rowptr[wid], end = rowptr[wid + 1];
  float inv = 1.0f / (denom[wid] + 1e-16f);
  float acc = 0.0f;

  if constexpr (FP8Y) {
    const unsigned char* Yb = (const unsigned char*)Ypv;
    for (int base = beg; base < end; base += 64) {
      int m = min(64, end - base);
      unsigned pk = (lane < m) ? csrp[base + lane] : 0u;
      #pragma unroll 8
      for (int q = 0; q < m; ++q) {
        unsigned u = __shfl(pk, q);
        float w = __half2float(__ushort_as_half((unsigned short)(u >> 16)));
        unsigned off = (u & 0xFFFFu) << 6;
        unsigned v8 = (unsigned)Yb[off + lane];           // 1B/lane, 1 line/edge
        float f = __builtin_amdgcn_cvt_f32_fp8(v8, 0);
        acc = fmaf(w, f, acc);
      }
    }
    // epilogue: lane owns channel choff+lane
    int c = choff + lane;
    float z = __half2float(Zb[(size_t)wid * dofull + c]);
    float o = fmaf(acc, inv, z);
    if constexpr (DO_BN) {
      float sc = g[c] * rsqrtf(vv[c] + BN_EPS);
      o = fmaxf(fmaf(o - mm[c], sc, bb[c]), 0.0f);
    }
    if constexpr (HALF_OUT) {
      ((__half*)outv)[(size_t)wid * dofull + c] = __float2half_rn(o);
    } else {
      ((float*)outv)[(size_t)wid * dofull + c] = o;
    }
  } else {
    const __half* Yp = (const __half*)Ypv;
    int grp = lane >> 5;     // edge slot 0..1
    int ch  = lane & 31;     // channel
    for (int base = beg; base < end; base += 64) {
      int m = min(64, end - base);
      unsigned pk = (lane < m) ? csrp[base + lane] : 0u;
      int iters = (m + 1) >> 1;
      #pragma unroll 8
      for (int q = 0; q < iters; ++q) {
        int ei = q * 2 + grp;
        unsigned u = __shfl(pk, ei);
        float w = (ei < m)
            ? __half2float(__ushort_as_half((unsigned short)(u >> 16))) : 0.0f;
        unsigned off = (u & 0xFFFFu) << 5;
        float f = __half2float(Yp[off + ch]);             // 2B/lane, 1 line/edge
        acc = fmaf(w, f, acc);
      }
    }
    acc += __shfl_xor(acc, 32);   // combine the two edge groups
    if (lane < 32) {
      int c = choff + ch;
      float z = __half2float(Zb[(size_t)wid * dofull + c]);
      float o = fmaf(acc, inv, z);
      if constexpr (DO_BN) {
        float sc = g[c] * rsqrtf(vv[c] + BN_EPS);
        o = fmaxf(fmaf(o - mm[c], sc, bb[c]), 0.0f);
      }
      if constexpr (HALF_OUT) {
        ((__half*)outv)[(size_t)wid * dofull + c] = __float2half_rn(o);
      } else {
        ((float*)outv)[(size_t)wid * dofull + c] = o;
      }
    }
  }
}

// ---------------------------------------------------------------------------
extern "C" void kernel_launch(void* const* d_in, const int* in_sizes, int n_in,
                              void* d_out, int out_size, void* d_ws, size_t ws_size,
                              hipStream_t stream) {
  const float* x   = (const float*)d_in[0];
  const int*   ei  = (const int*)d_in[1];
  const float* Wn0 = (const float*)d_in[2];
  const float* cn0 = (const float*)d_in[3];
  const float* Wr0 = (const float*)d_in[4];
  const float* cr0 = (const float*)d_in[5];
  const float* Wn1 = (const float*)d_in[6];
  const float* cn1 = (const float*)d_in[7];
  const float* Wr1 = (const float*)d_in[8];
  const float* cr1 = (const float*)d_in[9];
  const float* Wn2 = (const float*)d_in[10];
  const float* cn2 = (const float*)d_in[11];
  const float* Wr2 = (const float*)d_in[12];
  const float* cr2 = (const float*)d_in[13];
  const float* g0  = (const float*)d_in[14];
  const float* b0  = (const float*)d_in[15];
  const float* m0  = (const float*)d_in[16];
  const float* v0  = (const float*)d_in[17];
  const float* g1  = (const float*)d_in[18];
  const float* b1  = (const float*)d_in[19];
  const float* m1  = (const float*)d_in[20];
  const float* v1  = (const float*)d_in[21];

  const int* src = ei;
  const int* dst = ei + E_EDGES;

  char* p = (char*)d_ws;
  auto alloc = [&](size_t bytes) {
    char* r = p;
    p += (bytes + 255) & ~(size_t)255;
    return r;
  };
  __half*         P0      = (__half*)        alloc((size_t)N_NODES * 128 * 2);
  __half*         P1      = (__half*)        alloc((size_t)N_NODES * 128 * 2);
  __half*         A16     = (__half*)        alloc((size_t)N_NODES * 128 * 2);
  unsigned*       staging = (unsigned*)      alloc((size_t)NSB * NSUBL * SUBCAP * 4); // 8 MB
  int*            deg     = (int*)           alloc((size_t)N_NODES * 4);
  float*          denom   = (float*)         alloc((size_t)N_NODES * 4);
  int*            rowptr  = (int*)           alloc((size_t)(N_NODES + 1) * 4);
  int*            gcur    = (int*)           alloc((size_t)N_NODES * 4);
  int*            sbsum   = (int*)           alloc((size_t)NSB * 4);
  int*            sbbase  = (int*)           alloc((size_t)NSB * 4);
  int*            gc      = (int*)           alloc((size_t)(NSB * NSUBL * BSTR + 16) * 4);
  unsigned short* csrs16  = (unsigned short*)alloc((size_t)E_EDGES * 2);
  unsigned*       csrp    = (unsigned*)      alloc((size_t)E_EDGES * 4);
  __half*         WtN0    = (__half*)        alloc(128 * 128 * 2);
  __half*         WtR0    = (__half*)        alloc(128 * 128 * 2);
  __half*         WtN1    = (__half*)        alloc(128 * 128 * 2);
  __half*         WtR1    = (__half*)        alloc(128 * 128 * 2);
  __half*         WtN2    = (__half*)        alloc(64 * 128 * 2);
  __half*         WtR2    = (__half*)        alloc(64 * 128 * 2);
  float*          bias0   = (float*)         alloc(128 * 4);
  float*          bias1   = (float*)         alloc(128 * 4);
  float*          bias2   = (float*)         alloc(64 * 4);

  // fp8 Y planes (hidden layers) alias P0: xn dead after edge_weights.
  unsigned char* Y8 = (unsigned char*)P0;

  // overflow list aliases csrp (only written later by edge_weights)
  unsigned* ostage = (unsigned*)csrp;
  int*      ocnt   = gc + NSB * NSUBL * BSTR;   // covered by gc memset

  hipMemsetAsync(gc, 0, (size_t)(NSB * NSUBL * BSTR + 16) * 4, stream);

  const int node_grid = (N_NODES * 64 + 255) / 256;

  xn_norm<<<node_grid, 256, 0, stream>>>(x, P0, N_NODES);
  prep_weights<<<320, 256, 0, stream>>>(Wn0, Wr0, Wn1, Wr1, Wn2, Wr2,
                                        cn0, cr0, cn1, cr1, cn2, cr2,
                                        WtN0, WtR0, WtN1, WtR1, WtN2, WtR2,
                                        bias0, bias1, bias2);
  scatter_sb<<<SCGRID, 256, 0, stream>>>(src, dst, gc, staging, ocnt, ostage, E_EDGES);
  hist_sb<<<NSB, 256, 0, stream>>>(staging, gc, deg, sbsum, N_NODES);
  overflow_deg<<<64, 256, 0, stream>>>(ostage, ocnt, deg, sbsum);
  scan_sb<<<1, 128, 0, stream>>>(sbsum, sbbase, rowptr, N_NODES);
  rowptr_sb<<<NSB, 256, 0, stream>>>(deg, sbbase, rowptr, N_NODES);
  place_sb<<<NSB, 256, 0, stream>>>(staging, gc, rowptr, csrs16, gcur, N_NODES);
  overflow_place<<<64, 256, 0, stream>>>(ostage, ocnt, gcur, csrs16);
  edge_weights<<<node_grid, 256, 0, stream>>>(P0, rowptr, csrs16, csrp, denom, N_NODES);

  const int gemm_grid = (N_NODES + 63) / 64;

  // layer 0: H = x (f32), Y -> fp8 64-ch planes in Y8, Z -> P1, out -> A16
  gemm_dual_mfma<128, float, 1><<<gemm_grid, 256, 0, stream>>>(
      x, WtN0, WtR0, bias0, Y8, P1, N_NODES);
  for (int pass = 0; pass < 2; ++pass)
    agg_pass<true, true, true><<<node_grid, 256, 0, stream>>>(
        Y8 + (size_t)pass * N_NODES * 64, P1, rowptr, csrp, denom,
        g0, b0, m0, v0, A16, 128, pass * 64, N_NODES);

  // layer 1: H = A16 (fp16)
  gemm_dual_mfma<128, __half, 1><<<gemm_grid, 256, 0, stream>>>(
      A16, WtN1, WtR1, bias1, Y8, P1, N_NODES);
  for (int pass = 0; pass < 2; ++pass)
    agg_pass<true, true, true><<<node_grid, 256, 0, stream>>>(
        Y8 + (size_t)pass * N_NODES * 64, P1, rowptr, csrp, denom,
        g1, b1, m1, v1, A16, 128, pass * 64, N_NODES);

  // layer 2 (64-wide, fp16 planes for output precision, straight to d_out)
  gemm_dual_mfma<64, __half, 0><<<gemm_grid, 256, 0, stream>>>(
      A16, WtN2, WtR2, bias2, P0, P1, N_NODES);
  for (int pass = 0; pass < 2; ++pass)
    agg_pass<false, false, false><<<node_grid, 256, 0, stream>>>(
        P0 + (size_t)pass * N_NODES * 32, P1, rowptr, csrp, denom,
        nullptr, nullptr, nullptr, nullptr, d_out, 64, pass * 32, N_NODES);
}

// Round 20
// 453.661 us; speedup vs baseline: 1.3743x; 1.3743x over previous
//
#include <hip/hip_runtime.h>
#include <hip/hip_fp16.h>
#include <hip/hip_fp8.h>
#include <math.h>
#include <type_traits>

#define N_NODES 50000
#define E_EDGES 1600000
#define TAU     0.5f
#define BN_EPS  1e-5f
#define SBSH    9                        // 512 dst nodes per super-bucket
#define NSB     ((N_NODES + 511) >> 9)   // 98 super-buckets
#define NSUBL   8                        // staging sub-lists (spread cursor LINES)
#define SUBCAP  2560                     // entries per sub-list (mean 2048 + >10 sigma)
#define BINCAP  48                       // LDS bin capacity (mean 10.4, +11 sigma)
#define EPB     1024                     // edges per scatter block
#define SCGRID  ((E_EDGES + EPB - 1) / EPB)
#define BSTR    16                       // cursor stride in ints (64B/line)

typedef _Float16 f16x8 __attribute__((ext_vector_type(8)));
typedef float    f32x4 __attribute__((ext_vector_type(4)));
typedef float    f32x2 __attribute__((ext_vector_type(2)));

// dot of 16 fp8 pairs held in two int4 registers (OCP e4m3, HW cvt)
__device__ __forceinline__ float dot16_fp8(int4 a, int4 b) {
  unsigned wa[4] = {(unsigned)a.x, (unsigned)a.y, (unsigned)a.z, (unsigned)a.w};
  unsigned wb[4] = {(unsigned)b.x, (unsigned)b.y, (unsigned)b.z, (unsigned)b.w};
  float acc = 0.0f;
  #pragma unroll
  for (int i = 0; i < 4; ++i) {
    f32x2 alo = __builtin_amdgcn_cvt_pk_f32_fp8(wa[i], false);
    f32x2 ahi = __builtin_amdgcn_cvt_pk_f32_fp8(wa[i], true);
    f32x2 blo = __builtin_amdgcn_cvt_pk_f32_fp8(wb[i], false);
    f32x2 bhi = __builtin_amdgcn_cvt_pk_f32_fp8(wb[i], true);
    acc = fmaf(alo[0], blo[0], acc);
    acc = fmaf(alo[1], blo[1], acc);
    acc = fmaf(ahi[0], bhi[0], acc);
    acc = fmaf(ahi[1], bhi[1], acc);
  }
  return acc;
}

// ---------------------------------------------------------------------------
// 1) normalized FP8 features: xn8[i] = e4m3( x_i / (||x_i|| + 1e-12) )
__global__ __launch_bounds__(256) void xn_norm(
    const float* __restrict__ x, unsigned char* __restrict__ xn8, int n) {
  int wid  = (int)((blockIdx.x * blockDim.x + threadIdx.x) >> 6);
  int lane = threadIdx.x & 63;
  if (wid >= n) return;
  float2 v = ((const float2*)(x + (size_t)wid * 128))[lane];
  float s = v.x * v.x + v.y * v.y;
  #pragma unroll
  for (int off = 32; off; off >>= 1) s += __shfl_xor(s, off);
  float inv = 1.0f / (sqrtf(s) + 1e-12f);
  __hip_fp8_e4m3 q0(v.x * inv), q1(v.y * inv);
  uchar2 pk;
  pk.x = q0.__x; pk.y = q1.__x;
  ((uchar2*)(xn8 + (size_t)wid * 128))[lane] = pk;
}

// ---------------------------------------------------------------------------
// 2a) LDS-binned scatter (unchanged)
__global__ __launch_bounds__(256) void scatter_sb(
    const int* __restrict__ src, const int* __restrict__ dst,
    int* __restrict__ gc, unsigned* __restrict__ staging,
    int* __restrict__ ocnt, unsigned* __restrict__ ostage, int e) {
  __shared__ unsigned bins[NSB][BINCAP];
  __shared__ int bcount[NSB];
  const int tid  = threadIdx.x;
  const int wv   = tid >> 6;
  const int lane = tid & 63;
  const int sl   = blockIdx.x & (NSUBL - 1);
  for (int i = tid; i < NSB; i += 256) bcount[i] = 0;
  __syncthreads();

  int base = blockIdx.x * EPB;
  int bend = min(base + EPB, e);
  for (int i = base + tid; i < bend; i += 256) {
    int d = dst[i], s = src[i];
    int sb = d >> SBSH;
    int pos = atomicAdd(&bcount[sb], 1);
    if (pos < BINCAP) {
      bins[sb][pos] = (unsigned)s | ((unsigned)(d & 511) << 16);
    } else {
      int op = atomicAdd(ocnt, 1);
      ostage[op] = (unsigned)s | ((unsigned)d << 16);   // full dst
    }
  }
  __syncthreads();

  for (int sb = wv; sb < NSB; sb += 4) {
    int cnt = min(bcount[sb], BINCAP);
    if (cnt > 0) {
      int cell = sb * NSUBL + sl;
      int gbase = 0;
      if (lane == 0) gbase = atomicAdd(&gc[cell * BSTR], cnt);
      gbase = __shfl(gbase, 0);
      if (gbase + cnt <= SUBCAP) {
        if (lane < cnt)
          staging[(size_t)cell * SUBCAP + gbase + lane] = bins[sb][lane];
      } else if (lane < cnt) {
        unsigned u = bins[sb][lane];
        int op = atomicAdd(ocnt, 1);
        ostage[op] = (u & 0xFFFFu) | ((unsigned)((sb << SBSH) | (u >> 16)) << 16);
      }
    }
  }
}

// ---------------------------------------------------------------------------
// 2b) per-SB LDS histogram over the 8 sub-lists -> deg + SB total
__global__ __launch_bounds__(256) void hist_sb(
    const unsigned* __restrict__ staging, const int* __restrict__ gc,
    int* __restrict__ deg, int* __restrict__ sbsum, int n) {
  __shared__ int h[512];
  __shared__ int wt[4];
  int sb = blockIdx.x;
  for (int i = threadIdx.x; i < 512; i += 256) h[i] = 0;
  __syncthreads();
  for (int s = 0; s < NSUBL; ++s) {
    int cell = sb * NSUBL + s;
    int m = min(gc[cell * BSTR], SUBCAP);
    for (int i = threadIdx.x; i < m; i += 256)
      atomicAdd(&h[(staging[(size_t)cell * SUBCAP + i] >> 16) & 511], 1);
  }
  __syncthreads();
  int d0 = sb << SBSH;
  for (int i = threadIdx.x; i < 512; i += 256)
    if (d0 + i < n) deg[d0 + i] = h[i];
  int t = h[threadIdx.x] + h[threadIdx.x + 256];
  #pragma unroll
  for (int off = 32; off; off >>= 1) t += __shfl_xor(t, off);
  if ((threadIdx.x & 63) == 0) wt[threadIdx.x >> 6] = t;
  __syncthreads();
  if (threadIdx.x == 0) sbsum[sb] = wt[0] + wt[1] + wt[2] + wt[3];
}

// ---------------------------------------------------------------------------
// 2b') overflow patch (no-op when ocnt==0)
__global__ __launch_bounds__(256) void overflow_deg(
    const unsigned* __restrict__ ostage, const int* __restrict__ ocnt,
    int* __restrict__ deg, int* __restrict__ sbsum) {
  int m = *ocnt;
  for (int i = blockIdx.x * blockDim.x + threadIdx.x; i < m;
       i += gridDim.x * blockDim.x) {
    int d = (int)(ostage[i] >> 16);
    atomicAdd(&deg[d], 1);
    atomicAdd(&sbsum[d >> SBSH], 1);
  }
}

// ---------------------------------------------------------------------------
// 3a) exclusive scan over the 98 SB sums
__global__ void scan_sb(const int* __restrict__ sbsum, int* __restrict__ sbbase,
                        int* __restrict__ rowptr, int n) {
  __shared__ int part[128];
  int t = (int)threadIdx.x;
  int v = (t < NSB) ? sbsum[t] : 0;
  part[t] = v;
  __syncthreads();
  for (int off = 1; off < 128; off <<= 1) {
    int u = (t >= off) ? part[t - off] : 0;
    __syncthreads();
    part[t] += u;
    __syncthreads();
  }
  if (t < NSB) sbbase[t] = part[t] - v;
  if (t == 127) rowptr[n] = part[127];
}

// ---------------------------------------------------------------------------
// 3b) rowptr within SB: 512-element block scan (2 per thread)
__global__ __launch_bounds__(256) void rowptr_sb(
    const int* __restrict__ deg, const int* __restrict__ sbbase,
    int* __restrict__ rowptr, int n) {
  __shared__ int part[256];
  int sb = blockIdx.x;
  int d0 = sb << SBSH;
  int t = (int)threadIdx.x;
  int e0 = d0 + 2 * t;
  int v0 = (e0 < n) ? deg[e0] : 0;
  int v1 = (e0 + 1 < n) ? deg[e0 + 1] : 0;
  int s = v0 + v1;
  part[t] = s;
  __syncthreads();
  for (int off = 1; off < 256; off <<= 1) {
    int u = (t >= off) ? part[t - off] : 0;
    __syncthreads();
    part[t] += u;
    __syncthreads();
  }
  int ex = part[t] - s + sbbase[sb];
  if (e0 < n) rowptr[e0] = ex;
  if (e0 + 1 < n) rowptr[e0 + 1] = ex + v0;
}

// ---------------------------------------------------------------------------
// 2c) placement (unchanged)
__global__ __launch_bounds__(256) void place_sb(
    const unsigned* __restrict__ staging, const int* __restrict__ gc,
    const int* __restrict__ rowptr, unsigned short* __restrict__ csr16,
    int* __restrict__ gcur, int n) {
  __shared__ int cur[512];
  int sb = blockIdx.x;
  int d0 = sb << SBSH;
  for (int i = threadIdx.x; i < 512; i += 256)
    cur[i] = (d0 + i < n) ? rowptr[d0 + i] : 0;
  __syncthreads();
  for (int s = 0; s < NSUBL; ++s) {
    int cell = sb * NSUBL + s;
    int m = min(gc[cell * BSTR], SUBCAP);
    for (int i = threadIdx.x; i < m; i += 256) {
      unsigned u = staging[(size_t)cell * SUBCAP + i];
      int j = (u >> 16) & 511;
      int pos = atomicAdd(&cur[j], 1);
      csr16[pos] = (unsigned short)(u & 0xFFFFu);
    }
  }
  __syncthreads();
  for (int i = threadIdx.x; i < 512; i += 256)
    if (d0 + i < n) gcur[d0 + i] = cur[i];
}

// ---------------------------------------------------------------------------
// 2c') overflow placement (no-op when ocnt==0)
__global__ __launch_bounds__(256) void overflow_place(
    const unsigned* __restrict__ ostage, const int* __restrict__ ocnt,
    int* __restrict__ gcur, unsigned short* __restrict__ csr16) {
  int m = *ocnt;
  for (int i = blockIdx.x * blockDim.x + threadIdx.x; i < m;
       i += gridDim.x * blockDim.x) {
    unsigned u = ostage[i];
    int d = (int)(u >> 16);
    int pos = atomicAdd(&gcur[d], 1);
    csr16[pos] = (unsigned short)(u & 0xFFFFu);
  }
}

// ---------------------------------------------------------------------------
// 4) edge weights, dst-ordered, FP8 features: 8 lanes/edge, ONE int4 per
// lane per side (16 fp8 dims each) -> 128B/row gather (was 256B fp16).
__global__ __launch_bounds__(256) void edge_weights(
    const unsigned char* __restrict__ xn8, const int* __restrict__ rowptr,
    const unsigned short* __restrict__ csr_src16,
    unsigned* __restrict__ csrp, float* __restrict__ denom, int n) {
  int wid  = (int)((blockIdx.x * blockDim.x + threadIdx.x) >> 6);
  int lane = threadIdx.x & 63;
  if (wid >= n) return;
  int grp = lane >> 3;       // edge slot 0..7
  int sub = lane & 7;        // 16-dim slice
  int beg = rowptr[wid], end = rowptr[wid + 1];
  int4 xdv = ((const int4*)(xn8 + (size_t)wid * 128))[sub];
  float wsum = 0.0f;

  for (int base = beg; base < end; base += 64) {
    int m = min(64, end - base);
    int sv = (lane < m) ? (int)csr_src16[base + lane] : 0;
    int iters = (m + 7) >> 3;
    #pragma unroll 2
    for (int q = 0; q < iters; ++q) {
      int ei = q * 8 + grp;
      int s = __shfl(sv, ei);
      int4 xsv = ((const int4*)(xn8 + (size_t)s * 128))[sub];
      float dp = dot16_fp8(xsv, xdv);
      dp += __shfl_xor(dp, 1);
      dp += __shfl_xor(dp, 2);
      dp += __shfl_xor(dp, 4);
      bool valid = ei < m;
      float w = valid ? __expf(dp * (1.0f / TAU)) : 0.0f;
      wsum += w;
      if (valid && sub == 0) {
        unsigned w16 = (unsigned)__half_as_ushort(__float2half_rn(w));
        csrp[base + ei] = (unsigned)s | (w16 << 16);
      }
    }
  }
  wsum += __shfl_xor(wsum, 8);
  wsum += __shfl_xor(wsum, 16);
  wsum += __shfl_xor(wsum, 32);
  if (lane == 0) denom[wid] = wsum;
}

// ---------------------------------------------------------------------------
// 5a) weight prepack in MFMA fragment order (unchanged)
__global__ __launch_bounds__(256) void prep_weights(
    const float* __restrict__ Wn0, const float* __restrict__ Wr0,
    const float* __restrict__ Wn1, const float* __restrict__ Wr1,
    const float* __restrict__ Wn2, const float* __restrict__ Wr2,
    const float* __restrict__ cn0, const float* __restrict__ cr0,
    const float* __restrict__ cn1, const float* __restrict__ cr1,
    const float* __restrict__ cn2, const float* __restrict__ cr2,
    __half* __restrict__ WtN0, __half* __restrict__ WtR0,
    __half* __restrict__ WtN1, __half* __restrict__ WtR1,
    __half* __restrict__ WtN2, __half* __restrict__ WtR2,
    float* __restrict__ bias0, float* __restrict__ bias1,
    float* __restrict__ bias2) {
  int i = blockIdx.x * blockDim.x + threadIdx.x;
  const float* Ws[6] = {Wn0, Wr0, Wn1, Wr1, Wn2, Wr2};
  __half*     Wts[6] = {WtN0, WtR0, WtN1, WtR1, WtN2, WtR2};
  int seg = -1, off = 0;
  if (i < 65536)        { seg = i >> 14;               off = i & 16383; }
  else if (i < 81920)   { int j = i - 65536; seg = 4 + (j >> 13); off = j & 8191; }
  if (seg >= 0) {
    int DO = (seg < 4) ? 128 : 64;
    int c = off >> 7, k = off & 127;
    int t = c >> 4, kc = k >> 5, kgrp = (k >> 3) & 3, j = k & 7;
    int lane = (c & 15) | (kgrp << 4);
    int idx = (((t * 4 + kc) * 64 + lane) << 3) + j;
    Wts[seg][idx] = __float2half_rn(Ws[seg][(size_t)k * DO + c]);
  }
  if (i < 128) { bias0[i] = cn0[i] + cr0[i]; bias1[i] = cn1[i] + cr1[i]; }
  if (i < 64)  { bias2[i] = cn2[i] + cr2[i]; }
}

// ---------------------------------------------------------------------------
// 5b) dual MFMA GEMM (unchanged from R18)
template <int DO, typename TIN, int YMODE>
__global__ __launch_bounds__(256) void gemm_dual_mfma(
    const TIN* __restrict__ H, const __half* __restrict__ WfN,
    const __half* __restrict__ WfR, const float* __restrict__ bias,
    void* __restrict__ Yv, __half* __restrict__ Z, int n) {
  constexpr int NT = DO / 16;
  const int lane  = threadIdx.x & 63;
  const int w     = threadIdx.x >> 6;
  const int row0  = blockIdx.x * 64 + w * 16;
  const int col16 = lane & 15;
  const int kgrp  = (lane >> 4) * 8;
  const size_t arow = (size_t)min(row0 + col16, n - 1);

  f32x4 acc[2][NT];
  #pragma unroll
  for (int m = 0; m < 2; ++m)
    #pragma unroll
    for (int t = 0; t < NT; ++t) acc[m][t] = (f32x4){0.f, 0.f, 0.f, 0.f};

  #pragma unroll
  for (int kc = 0; kc < 4; ++kc) {
    f16x8 a;
    if constexpr (std::is_same<TIN, float>::value) {
      const float* hp = H + arow * 128 + kc * 32 + kgrp;
      float4 f0 = *(const float4*)hp;
      float4 f1 = *(const float4*)(hp + 4);
      a[0] = (_Float16)f0.x; a[1] = (_Float16)f0.y;
      a[2] = (_Float16)f0.z; a[3] = (_Float16)f0.w;
      a[4] = (_Float16)f1.x; a[5] = (_Float16)f1.y;
      a[6] = (_Float16)f1.z; a[7] = (_Float16)f1.w;
    } else {
      a = *(const f16x8*)(H + arow * 128 + kc * 32 + kgrp);
    }
    const f16x8* bN = (const f16x8*)(WfN + ((size_t)(kc * 64 + lane) << 3));
    const f16x8* bR = (const f16x8*)(WfR + ((size_t)(kc * 64 + lane) << 3));
    #pragma unroll
    for (int t = 0; t < NT; ++t) {
      f16x8 b = bN[t * 256];
      acc[0][t] = __builtin_amdgcn_mfma_f32_16x16x32_f16(a, b, acc[0][t], 0, 0, 0);
    }
    #pragma unroll
    for (int t = 0; t < NT; ++t) {
      f16x8 b = bR[t * 256];
      acc[1][t] = __builtin_amdgcn_mfma_f32_16x16x32_f16(a, b, acc[1][t], 0, 0, 0);
    }
  }

  const int rbase = (lane >> 4) * 4;
  #pragma unroll
  for (int t = 0; t < NT; ++t) {
    int col = t * 16 + col16;
    float bz = bias[col];
    #pragma unroll
    for (int j = 0; j < 4; ++j) {
      int row = row0 + rbase + j;
      if (row < n) {
        if constexpr (YMODE == 1) {
          int pidx = col >> 6, incol = col & 63;
          __hip_fp8_e4m3 q(acc[0][t][j]);
          ((unsigned char*)Yv)[((size_t)pidx * n + row) * 64 + incol] = q.__x;
        } else {
          int pidx = col >> 5, incol = col & 31;
          ((__half*)Yv)[((size_t)pidx * n + row) * 32 + incol] =
              __float2half_rn(acc[0][t][j]);
        }
        Z[(size_t)row * DO + col] = __float2half_rn(acc[1][t][j] + bz);
      }
    }
  }
}

// ---------------------------------------------------------------------------
// 6) aggregation pass over ONE plane (R18 structure: 16 edges in flight,
// 4 lanes/edge, int4/lane; fp8 unpack via HW cvt_pk_f32_fp8).
template <bool DO_BN, bool HALF_OUT, bool FP8Y>
__global__ __launch_bounds__(256) void agg_pass(
    const void* __restrict__ Ypv, const __half* __restrict__ Zb,
    const int* __restrict__ rowptr, const unsigned* __restrict__ csrp,
    const float* __restrict__ denom,
    const float* __restrict__ g, const float* __restrict__ bb,
    const float* __restrict__ mm, const float* __restrict__ vv,
    void* __restrict__ outv, int dofull, int choff, int n) {
  constexpr int CH = FP8Y ? 16 : 8;    // channels per lane
  int wid  = (int)((blockIdx.x * blockDim.x + threadIdx.x) >> 6);
  int lane = threadIdx.x & 63;
  if (wid >= n) return;
  int grp = lane >> 2;     // edge slot 0..15
  int sub = lane & 3;      // channel group 0..3
  int beg = rowptr[wid], end = rowptr[wid + 1];
  float inv = 1.0f / (denom[wid] + 1e-16f);

  float a[CH];
  #pragma unroll
  for (int k = 0; k < CH; ++k) a[k] = 0.0f;

  for (int base = beg; base < end; base += 64) {
    int m = min(64, end - base);
    unsigned pk = (lane < m) ? csrp[base + lane] : 0u;   // w=0 when inactive
    int iters = (m + 15) >> 4;
    #pragma unroll 4
    for (int q = 0; q < iters; ++q) {
      unsigned u = __shfl(pk, q * 16 + grp);
      int   s = (int)(u & 0xFFFFu);
      float w = __half2float(__ushort_as_half((unsigned short)(u >> 16)));
      if constexpr (FP8Y) {
        int4 raw = ((const int4*)((const unsigned char*)Ypv + (size_t)s * 64))[sub];
        unsigned ww[4] = {(unsigned)raw.x, (unsigned)raw.y,
                          (unsigned)raw.z, (unsigned)raw.w};
        #pragma unroll
        for (int wi = 0; wi < 4; ++wi) {
          f32x2 lo = __builtin_amdgcn_cvt_pk_f32_fp8(ww[wi], false);
          f32x2 hi = __builtin_amdgcn_cvt_pk_f32_fp8(ww[wi], true);
          a[wi * 4 + 0] = fmaf(w, lo[0], a[wi * 4 + 0]);
          a[wi * 4 + 1] = fmaf(w, lo[1], a[wi * 4 + 1]);
          a[wi * 4 + 2] = fmaf(w, hi[0], a[wi * 4 + 2]);
          a[wi * 4 + 3] = fmaf(w, hi[1], a[wi * 4 + 3]);
        }
      } else {
        int4 raw = ((const int4*)((const __half*)Ypv + (size_t)s * 32))[sub];
        const __half2* hh = (const __half2*)&raw;
        #pragma unroll
        for (int k = 0; k < 4; ++k) {
          float2 f = __half22float2(hh[k]);
          a[2 * k]     = fmaf(w, f.x, a[2 * k]);
          a[2 * k + 1] = fmaf(w, f.y, a[2 * k + 1]);
        }
      }
    }
  }
  #pragma unroll
  for (int off = 32; off >= 4; off >>= 1) {
    #pragma unroll
    for (int k = 0; k < CH; ++k) a[k] += __shfl_xor(a[k], off);
  }

  if (lane < 4) {
    int c = choff + sub * CH;
    float o[CH];
    const int4* zp = (const int4*)(Zb + (size_t)wid * dofull + c);
    #pragma unroll
    for (int v = 0; v < CH / 8; ++v) {
      int4 zr = zp[v];
      const __half2* zh = (const __half2*)&zr;
      #pragma unroll
      for (int k = 0; k < 4; ++k) {
        float2 z = __half22float2(zh[k]);
        o[v * 8 + 2 * k]     = fmaf(a[v * 8 + 2 * k], inv, z.x);
        o[v * 8 + 2 * k + 1] = fmaf(a[v * 8 + 2 * k + 1], inv, z.y);
      }
    }
    if constexpr (DO_BN) {
      #pragma unroll
      for (int k = 0; k < CH; ++k) {
        float sc = g[c + k] * rsqrtf(vv[c + k] + BN_EPS);
        o[k] = fmaxf(fmaf(o[k] - mm[c + k], sc, bb[c + k]), 0.0f);
      }
    }
    if constexpr (HALF_OUT) {
      #pragma unroll
      for (int v = 0; v < CH / 8; ++v) {
        __half2 p0 = __floats2half2_rn(o[v * 8 + 0], o[v * 8 + 1]);
        __half2 p1 = __floats2half2_rn(o[v * 8 + 2], o[v * 8 + 3]);
        __half2 p2 = __floats2half2_rn(o[v * 8 + 4], o[v * 8 + 5]);
        __half2 p3 = __floats2half2_rn(o[v * 8 + 6], o[v * 8 + 7]);
        int4 pk4;
        pk4.x = *(int*)&p0; pk4.y = *(int*)&p1;
        pk4.z = *(int*)&p2; pk4.w = *(int*)&p3;
        ((int4*)((__half*)outv + (size_t)wid * dofull + c))[v] = pk4;
      }
    } else {
      float* op = (float*)outv + (size_t)wid * dofull + c;
      #pragma unroll
      for (int v = 0; v < CH / 4; ++v)
        ((float4*)op)[v] = make_float4(o[v * 4], o[v * 4 + 1],
                                       o[v * 4 + 2], o[v * 4 + 3]);
    }
  }
}

// ---------------------------------------------------------------------------
extern "C" void kernel_launch(void* const* d_in, const int* in_sizes, int n_in,
                              void* d_out, int out_size, void* d_ws, size_t ws_size,
                              hipStream_t stream) {
  const float* x   = (const float*)d_in[0];
  const int*   ei  = (const int*)d_in[1];
  const float* Wn0 = (const float*)d_in[2];
  const float* cn0 = (const float*)d_in[3];
  const float* Wr0 = (const float*)d_in[4];
  const float* cr0 = (const float*)d_in[5];
  const float* Wn1 = (const float*)d_in[6];
  const float* cn1 = (const float*)d_in[7];
  const float* Wr1 = (const float*)d_in[8];
  const float* cr1 = (const float*)d_in[9];
  const float* Wn2 = (const float*)d_in[10];
  const float* cn2 = (const float*)d_in[11];
  const float* Wr2 = (const float*)d_in[12];
  const float* cr2 = (const float*)d_in[13];
  const float* g0  = (const float*)d_in[14];
  const float* b0  = (const float*)d_in[15];
  const float* m0  = (const float*)d_in[16];
  const float* v0  = (const float*)d_in[17];
  const float* g1  = (const float*)d_in[18];
  const float* b1  = (const float*)d_in[19];
  const float* m1  = (const float*)d_in[20];
  const float* v1  = (const float*)d_in[21];

  const int* src = ei;
  const int* dst = ei + E_EDGES;

  char* p = (char*)d_ws;
  auto alloc = [&](size_t bytes) {
    char* r = p;
    p += (bytes + 255) & ~(size_t)255;
    return r;
  };
  __half*         P0      = (__half*)        alloc((size_t)N_NODES * 128 * 2);
  __half*         P1      = (__half*)        alloc((size_t)N_NODES * 128 * 2);
  __half*         A16     = (__half*)        alloc((size_t)N_NODES * 128 * 2);
  unsigned*       staging = (unsigned*)      alloc((size_t)NSB * NSUBL * SUBCAP * 4); // 8 MB
  int*            deg     = (int*)           alloc((size_t)N_NODES * 4);
  float*          denom   = (float*)         alloc((size_t)N_NODES * 4);
  int*            rowptr  = (int*)           alloc((size_t)(N_NODES + 1) * 4);
  int*            gcur    = (int*)           alloc((size_t)N_NODES * 4);
  int*            sbsum   = (int*)           alloc((size_t)NSB * 4);
  int*            sbbase  = (int*)           alloc((size_t)NSB * 4);
  int*            gc      = (int*)           alloc((size_t)(NSB * NSUBL * BSTR + 16) * 4);
  unsigned short* csrs16  = (unsigned short*)alloc((size_t)E_EDGES * 2);
  unsigned*       csrp    = (unsigned*)      alloc((size_t)E_EDGES * 4);
  __half*         WtN0    = (__half*)        alloc(128 * 128 * 2);
  __half*         WtR0    = (__half*)        alloc(128 * 128 * 2);
  __half*         WtN1    = (__half*)        alloc(128 * 128 * 2);
  __half*         WtR1    = (__half*)        alloc(128 * 128 * 2);
  __half*         WtN2    = (__half*)        alloc(64 * 128 * 2);
  __half*         WtR2    = (__half*)        alloc(64 * 128 * 2);
  float*          bias0   = (float*)         alloc(128 * 4);
  float*          bias1   = (float*)         alloc(128 * 4);
  float*          bias2   = (float*)         alloc(64 * 4);

  // xn8 (6.4 MB) and later the fp8 Y planes (6.4 MB) both live in P0
  // (sequential lifetimes: xn8 dead after edge_weights, before first gemm).
  unsigned char* xn8 = (unsigned char*)P0;
  unsigned char* Y8  = (unsigned char*)P0;

  // overflow list aliases csrp (only written later by edge_weights)
  unsigned* ostage = (unsigned*)csrp;
  int*      ocnt   = gc + NSB * NSUBL * BSTR;   // covered by gc memset

  hipMemsetAsync(gc, 0, (size_t)(NSB * NSUBL * BSTR + 16) * 4, stream);

  const int node_grid = (N_NODES * 64 + 255) / 256;

  xn_norm<<<node_grid, 256, 0, stream>>>(x, xn8, N_NODES);
  prep_weights<<<320, 256, 0, stream>>>(Wn0, Wr0, Wn1, Wr1, Wn2, Wr2,
                                        cn0, cr0, cn1, cr1, cn2, cr2,
                                        WtN0, WtR0, WtN1, WtR1, WtN2, WtR2,
                                        bias0, bias1, bias2);
  scatter_sb<<<SCGRID, 256, 0, stream>>>(src, dst, gc, staging, ocnt, ostage, E_EDGES);
  hist_sb<<<NSB, 256, 0, stream>>>(staging, gc, deg, sbsum, N_NODES);
  overflow_deg<<<64, 256, 0, stream>>>(ostage, ocnt, deg, sbsum);
  scan_sb<<<1, 128, 0, stream>>>(sbsum, sbbase, rowptr, N_NODES);
  rowptr_sb<<<NSB, 256, 0, stream>>>(deg, sbbase, rowptr, N_NODES);
  place_sb<<<NSB, 256, 0, stream>>>(staging, gc, rowptr, csrs16, gcur, N_NODES);
  overflow_place<<<64, 256, 0, stream>>>(ostage, ocnt, gcur, csrs16);
  edge_weights<<<node_grid, 256, 0, stream>>>(xn8, rowptr, csrs16, csrp, denom, N_NODES);

  const int gemm_grid = (N_NODES + 63) / 64;

  // layer 0: H = x (f32), Y -> fp8 64-ch planes in Y8, Z -> P1, out -> A16
  gemm_dual_mfma<128, float, 1><<<gemm_grid, 256, 0, stream>>>(
      x, WtN0, WtR0, bias0, Y8, P1, N_NODES);
  for (int pass = 0; pass < 2; ++pass)
    agg_pass<true, true, true><<<node_grid, 256, 0, stream>>>(
        Y8 + (size_t)pass * N_NODES * 64, P1, rowptr, csrp, denom,
        g0, b0, m0, v0, A16, 128, pass * 64, N_NODES);

  // layer 1: H = A16 (fp16)
  gemm_dual_mfma<128, __half, 1><<<gemm_grid, 256, 0, stream>>>(
      A16, WtN1, WtR1, bias1, Y8, P1, N_NODES);
  for (int pass = 0; pass < 2; ++pass)
    agg_pass<true, true, true><<<node_grid, 256, 0, stream>>>(
        Y8 + (size_t)pass * N_NODES * 64, P1, rowptr, csrp, denom,
        g1, b1, m1, v1, A16, 128, pass * 64, N_NODES);

  // layer 2 (64-wide, fp16 planes for output precision, straight to d_out)
  gemm_dual_mfma<64, __half, 0><<<gemm_grid, 256, 0, stream>>>(
      A16, WtN2, WtR2, bias2, P0, P1, N_NODES);
  for (int pass = 0; pass < 2; ++pass)
    agg_pass<false, false, false><<<node_grid, 256, 0, stream>>>(
        P0 + (size_t)pass * N_NODES * 32, P1, rowptr, csrp, denom,
        nullptr, nullptr, nullptr, nullptr, d_out, 64, pass * 32, N_NODES);
}

// Round 21
// 359.262 us; speedup vs baseline: 1.7354x; 1.2628x over previous
//
#include <hip/hip_runtime.h>
#include <hip/hip_fp16.h>
#include <hip/hip_fp8.h>
#include <math.h>
#include <type_traits>

#define N_NODES 50000
#define E_EDGES 1600000
#define TAU     0.5f
#define BN_EPS  1e-5f
#define SBSH    9                        // 512 dst nodes per super-bucket
#define NSB     ((N_NODES + 511) >> 9)   // 98 super-buckets
#define NSUBL   8                        // staging sub-lists (spread cursor LINES)
#define SUBCAP  2560                     // entries per sub-list (mean 2048 + >10 sigma)
#define BINCAP  48                       // LDS bin capacity (mean 10.4, +11 sigma)
#define EPB     1024                     // edges per scatter block
#define SCGRID  ((E_EDGES + EPB - 1) / EPB)
#define BSTR    16                       // cursor stride in ints (64B/line)

typedef _Float16 f16x8 __attribute__((ext_vector_type(8)));
typedef float    f32x4 __attribute__((ext_vector_type(4)));
typedef float    f32x2 __attribute__((ext_vector_type(2)));

// dot of 16 fp8 pairs held in two int4 registers (OCP e4m3, HW cvt)
__device__ __forceinline__ float dot16_fp8(int4 a, int4 b) {
  unsigned wa[4] = {(unsigned)a.x, (unsigned)a.y, (unsigned)a.z, (unsigned)a.w};
  unsigned wb[4] = {(unsigned)b.x, (unsigned)b.y, (unsigned)b.z, (unsigned)b.w};
  float acc = 0.0f;
  #pragma unroll
  for (int i = 0; i < 4; ++i) {
    f32x2 alo = __builtin_amdgcn_cvt_pk_f32_fp8(wa[i], false);
    f32x2 ahi = __builtin_amdgcn_cvt_pk_f32_fp8(wa[i], true);
    f32x2 blo = __builtin_amdgcn_cvt_pk_f32_fp8(wb[i], false);
    f32x2 bhi = __builtin_amdgcn_cvt_pk_f32_fp8(wb[i], true);
    acc = fmaf(alo[0], blo[0], acc);
    acc = fmaf(alo[1], blo[1], acc);
    acc = fmaf(ahi[0], bhi[0], acc);
    acc = fmaf(ahi[1], bhi[1], acc);
  }
  return acc;
}

// ---------------------------------------------------------------------------
// 1) normalized FP8 features: xn8[i] = e4m3( x_i / (||x_i|| + 1e-12) )
__global__ __launch_bounds__(256) void xn_norm(
    const float* __restrict__ x, unsigned char* __restrict__ xn8, int n) {
  int wid  = (int)((blockIdx.x * blockDim.x + threadIdx.x) >> 6);
  int lane = threadIdx.x & 63;
  if (wid >= n) return;
  float2 v = ((const float2*)(x + (size_t)wid * 128))[lane];
  float s = v.x * v.x + v.y * v.y;
  #pragma unroll
  for (int off = 32; off; off >>= 1) s += __shfl_xor(s, off);
  float inv = 1.0f / (sqrtf(s) + 1e-12f);
  __hip_fp8_e4m3 q0(v.x * inv), q1(v.y * inv);
  uchar2 pk;
  pk.x = q0.__x; pk.y = q1.__x;
  ((uchar2*)(xn8 + (size_t)wid * 128))[lane] = pk;
}

// ---------------------------------------------------------------------------
// 2a) LDS-binned scatter (unchanged)
__global__ __launch_bounds__(256) void scatter_sb(
    const int* __restrict__ src, const int* __restrict__ dst,
    int* __restrict__ gc, unsigned* __restrict__ staging,
    int* __restrict__ ocnt, unsigned* __restrict__ ostage, int e) {
  __shared__ unsigned bins[NSB][BINCAP];
  __shared__ int bcount[NSB];
  const int tid  = threadIdx.x;
  const int wv   = tid >> 6;
  const int lane = tid & 63;
  const int sl   = blockIdx.x & (NSUBL - 1);
  for (int i = tid; i < NSB; i += 256) bcount[i] = 0;
  __syncthreads();

  int base = blockIdx.x * EPB;
  int bend = min(base + EPB, e);
  for (int i = base + tid; i < bend; i += 256) {
    int d = dst[i], s = src[i];
    int sb = d >> SBSH;
    int pos = atomicAdd(&bcount[sb], 1);
    if (pos < BINCAP) {
      bins[sb][pos] = (unsigned)s | ((unsigned)(d & 511) << 16);
    } else {
      int op = atomicAdd(ocnt, 1);
      ostage[op] = (unsigned)s | ((unsigned)d << 16);   // full dst
    }
  }
  __syncthreads();

  for (int sb = wv; sb < NSB; sb += 4) {
    int cnt = min(bcount[sb], BINCAP);
    if (cnt > 0) {
      int cell = sb * NSUBL + sl;
      int gbase = 0;
      if (lane == 0) gbase = atomicAdd(&gc[cell * BSTR], cnt);
      gbase = __shfl(gbase, 0);
      if (gbase + cnt <= SUBCAP) {
        if (lane < cnt)
          staging[(size_t)cell * SUBCAP + gbase + lane] = bins[sb][lane];
      } else if (lane < cnt) {
        unsigned u = bins[sb][lane];
        int op = atomicAdd(ocnt, 1);
        ostage[op] = (u & 0xFFFFu) | ((unsigned)((sb << SBSH) | (u >> 16)) << 16);
      }
    }
  }
}

// ---------------------------------------------------------------------------
// 2b) per-SB LDS histogram over the 8 sub-lists -> deg + SB total
__global__ __launch_bounds__(256) void hist_sb(
    const unsigned* __restrict__ staging, const int* __restrict__ gc,
    int* __restrict__ deg, int* __restrict__ sbsum, int n) {
  __shared__ int h[512];
  __shared__ int wt[4];
  int sb = blockIdx.x;
  for (int i = threadIdx.x; i < 512; i += 256) h[i] = 0;
  __syncthreads();
  for (int s = 0; s < NSUBL; ++s) {
    int cell = sb * NSUBL + s;
    int m = min(gc[cell * BSTR], SUBCAP);
    for (int i = threadIdx.x; i < m; i += 256)
      atomicAdd(&h[(staging[(size_t)cell * SUBCAP + i] >> 16) & 511], 1);
  }
  __syncthreads();
  int d0 = sb << SBSH;
  for (int i = threadIdx.x; i < 512; i += 256)
    if (d0 + i < n) deg[d0 + i] = h[i];
  int t = h[threadIdx.x] + h[threadIdx.x + 256];
  #pragma unroll
  for (int off = 32; off; off >>= 1) t += __shfl_xor(t, off);
  if ((threadIdx.x & 63) == 0) wt[threadIdx.x >> 6] = t;
  __syncthreads();
  if (threadIdx.x == 0) sbsum[sb] = wt[0] + wt[1] + wt[2] + wt[3];
}

// ---------------------------------------------------------------------------
// 2b') overflow patch (no-op when ocnt==0)
__global__ __launch_bounds__(256) void overflow_deg(
    const unsigned* __restrict__ ostage, const int* __restrict__ ocnt,
    int* __restrict__ deg, int* __restrict__ sbsum) {
  int m = *ocnt;
  for (int i = blockIdx.x * blockDim.x + threadIdx.x; i < m;
       i += gridDim.x * blockDim.x) {
    int d = (int)(ostage[i] >> 16);
    atomicAdd(&deg[d], 1);
    atomicAdd(&sbsum[d >> SBSH], 1);
  }
}

// ---------------------------------------------------------------------------
// 3a) exclusive scan over the 98 SB sums
__global__ void scan_sb(const int* __restrict__ sbsum, int* __restrict__ sbbase,
                        int* __restrict__ rowptr, int n) {
  __shared__ int part[128];
  int t = (int)threadIdx.x;
  int v = (t < NSB) ? sbsum[t] : 0;
  part[t] = v;
  __syncthreads();
  for (int off = 1; off < 128; off <<= 1) {
    int u = (t >= off) ? part[t - off] : 0;
    __syncthreads();
    part[t] += u;
    __syncthreads();
  }
  if (t < NSB) sbbase[t] = part[t] - v;
  if (t == 127) rowptr[n] = part[127];
}

// ---------------------------------------------------------------------------
// 3b) rowptr within SB: 512-element block scan (2 per thread)
__global__ __launch_bounds__(256) void rowptr_sb(
    const int* __restrict__ deg, const int* __restrict__ sbbase,
    int* __restrict__ rowptr, int n) {
  __shared__ int part[256];
  int sb = blockIdx.x;
  int d0 = sb << SBSH;
  int t = (int)threadIdx.x;
  int e0 = d0 + 2 * t;
  int v0 = (e0 < n) ? deg[e0] : 0;
  int v1 = (e0 + 1 < n) ? deg[e0 + 1] : 0;
  int s = v0 + v1;
  part[t] = s;
  __syncthreads();
  for (int off = 1; off < 256; off <<= 1) {
    int u = (t >= off) ? part[t - off] : 0;
    __syncthreads();
    part[t] += u;
    __syncthreads();
  }
  int ex = part[t] - s + sbbase[sb];
  if (e0 < n) rowptr[e0] = ex;
  if (e0 + 1 < n) rowptr[e0 + 1] = ex + v0;
}

// ---------------------------------------------------------------------------
// 2c) placement (unchanged)
__global__ __launch_bounds__(256) void place_sb(
    const unsigned* __restrict__ staging, const int* __restrict__ gc,
    const int* __restrict__ rowptr, unsigned short* __restrict__ csr16,
    int* __restrict__ gcur, int n) {
  __shared__ int cur[512];
  int sb = blockIdx.x;
  int d0 = sb << SBSH;
  for (int i = threadIdx.x; i < 512; i += 256)
    cur[i] = (d0 + i < n) ? rowptr[d0 + i] : 0;
  __syncthreads();
  for (int s = 0; s < NSUBL; ++s) {
    int cell = sb * NSUBL + s;
    int m = min(gc[cell * BSTR], SUBCAP);
    for (int i = threadIdx.x; i < m; i += 256) {
      unsigned u = staging[(size_t)cell * SUBCAP + i];
      int j = (u >> 16) & 511;
      int pos = atomicAdd(&cur[j], 1);
      csr16[pos] = (unsigned short)(u & 0xFFFFu);
    }
  }
  __syncthreads();
  for (int i = threadIdx.x; i < 512; i += 256)
    if (d0 + i < n) gcur[d0 + i] = cur[i];
}

// ---------------------------------------------------------------------------
// 2c') overflow placement (no-op when ocnt==0)
__global__ __launch_bounds__(256) void overflow_place(
    const unsigned* __restrict__ ostage, const int* __restrict__ ocnt,
    int* __restrict__ gcur, unsigned short* __restrict__ csr16) {
  int m = *ocnt;
  for (int i = blockIdx.x * blockDim.x + threadIdx.x; i < m;
       i += gridDim.x * blockDim.x) {
    unsigned u = ostage[i];
    int d = (int)(u >> 16);
    int pos = atomicAdd(&gcur[d], 1);
    csr16[pos] = (unsigned short)(u & 0xFFFFu);
  }
}

// ---------------------------------------------------------------------------
// 4) edge weights, dst-ordered, FP8 features (unchanged from R20)
__global__ __launch_bounds__(256) void edge_weights(
    const unsigned char* __restrict__ xn8, const int* __restrict__ rowptr,
    const unsigned short* __restrict__ csr_src16,
    unsigned* __restrict__ csrp, float* __restrict__ denom, int n) {
  int wid  = (int)((blockIdx.x * blockDim.x + threadIdx.x) >> 6);
  int lane = threadIdx.x & 63;
  if (wid >= n) return;
  int grp = lane >> 3;       // edge slot 0..7
  int sub = lane & 7;        // 16-dim slice
  int beg = rowptr[wid], end = rowptr[wid + 1];
  int4 xdv = ((const int4*)(xn8 + (size_t)wid * 128))[sub];
  float wsum = 0.0f;

  for (int base = beg; base < end; base += 64) {
    int m = min(64, end - base);
    int sv = (lane < m) ? (int)csr_src16[base + lane] : 0;
    int iters = (m + 7) >> 3;
    #pragma unroll 2
    for (int q = 0; q < iters; ++q) {
      int ei = q * 8 + grp;
      int s = __shfl(sv, ei);
      int4 xsv = ((const int4*)(xn8 + (size_t)s * 128))[sub];
      float dp = dot16_fp8(xsv, xdv);
      dp += __shfl_xor(dp, 1);
      dp += __shfl_xor(dp, 2);
      dp += __shfl_xor(dp, 4);
      bool valid = ei < m;
      float w = valid ? __expf(dp * (1.0f / TAU)) : 0.0f;
      wsum += w;
      if (valid && sub == 0) {
        unsigned w16 = (unsigned)__half_as_ushort(__float2half_rn(w));
        csrp[base + ei] = (unsigned)s | (w16 << 16);
      }
    }
  }
  wsum += __shfl_xor(wsum, 8);
  wsum += __shfl_xor(wsum, 16);
  wsum += __shfl_xor(wsum, 32);
  if (lane == 0) denom[wid] = wsum;
}

// ---------------------------------------------------------------------------
// 5a) weight prepack in MFMA fragment order (unchanged)
__global__ __launch_bounds__(256) void prep_weights(
    const float* __restrict__ Wn0, const float* __restrict__ Wr0,
    const float* __restrict__ Wn1, const float* __restrict__ Wr1,
    const float* __restrict__ Wn2, const float* __restrict__ Wr2,
    const float* __restrict__ cn0, const float* __restrict__ cr0,
    const float* __restrict__ cn1, const float* __restrict__ cr1,
    const float* __restrict__ cn2, const float* __restrict__ cr2,
    __half* __restrict__ WtN0, __half* __restrict__ WtR0,
    __half* __restrict__ WtN1, __half* __restrict__ WtR1,
    __half* __restrict__ WtN2, __half* __restrict__ WtR2,
    float* __restrict__ bias0, float* __restrict__ bias1,
    float* __restrict__ bias2) {
  int i = blockIdx.x * blockDim.x + threadIdx.x;
  const float* Ws[6] = {Wn0, Wr0, Wn1, Wr1, Wn2, Wr2};
  __half*     Wts[6] = {WtN0, WtR0, WtN1, WtR1, WtN2, WtR2};
  int seg = -1, off = 0;
  if (i < 65536)        { seg = i >> 14;               off = i & 16383; }
  else if (i < 81920)   { int j = i - 65536; seg = 4 + (j >> 13); off = j & 8191; }
  if (seg >= 0) {
    int DO = (seg < 4) ? 128 : 64;
    int c = off >> 7, k = off & 127;
    int t = c >> 4, kc = k >> 5, kgrp = (k >> 3) & 3, j = k & 7;
    int lane = (c & 15) | (kgrp << 4);
    int idx = (((t * 4 + kc) * 64 + lane) << 3) + j;
    Wts[seg][idx] = __float2half_rn(Ws[seg][(size_t)k * DO + c]);
  }
  if (i < 128) { bias0[i] = cn0[i] + cr0[i]; bias1[i] = cn1[i] + cr1[i]; }
  if (i < 64)  { bias2[i] = cn2[i] + cr2[i]; }
}

// ---------------------------------------------------------------------------
// 5b) dual MFMA GEMM. YMODE=1: Y as fp8 CONTIGUOUS 128-ch rows (128B burst
// per agg gather). YMODE=0: Y as fp16 contiguous 64-ch rows.
template <int DO, typename TIN, int YMODE>
__global__ __launch_bounds__(256) void gemm_dual_mfma(
    const TIN* __restrict__ H, const __half* __restrict__ WfN,
    const __half* __restrict__ WfR, const float* __restrict__ bias,
    void* __restrict__ Yv, __half* __restrict__ Z, int n) {
  constexpr int NT = DO / 16;
  const int lane  = threadIdx.x & 63;
  const int w     = threadIdx.x >> 6;
  const int row0  = blockIdx.x * 64 + w * 16;
  const int col16 = lane & 15;
  const int kgrp  = (lane >> 4) * 8;
  const size_t arow = (size_t)min(row0 + col16, n - 1);

  f32x4 acc[2][NT];
  #pragma unroll
  for (int m = 0; m < 2; ++m)
    #pragma unroll
    for (int t = 0; t < NT; ++t) acc[m][t] = (f32x4){0.f, 0.f, 0.f, 0.f};

  #pragma unroll
  for (int kc = 0; kc < 4; ++kc) {
    f16x8 a;
    if constexpr (std::is_same<TIN, float>::value) {
      const float* hp = H + arow * 128 + kc * 32 + kgrp;
      float4 f0 = *(const float4*)hp;
      float4 f1 = *(const float4*)(hp + 4);
      a[0] = (_Float16)f0.x; a[1] = (_Float16)f0.y;
      a[2] = (_Float16)f0.z; a[3] = (_Float16)f0.w;
      a[4] = (_Float16)f1.x; a[5] = (_Float16)f1.y;
      a[6] = (_Float16)f1.z; a[7] = (_Float16)f1.w;
    } else {
      a = *(const f16x8*)(H + arow * 128 + kc * 32 + kgrp);
    }
    const f16x8* bN = (const f16x8*)(WfN + ((size_t)(kc * 64 + lane) << 3));
    const f16x8* bR = (const f16x8*)(WfR + ((size_t)(kc * 64 + lane) << 3));
    #pragma unroll
    for (int t = 0; t < NT; ++t) {
      f16x8 b = bN[t * 256];
      acc[0][t] = __builtin_amdgcn_mfma_f32_16x16x32_f16(a, b, acc[0][t], 0, 0, 0);
    }
    #pragma unroll
    for (int t = 0; t < NT; ++t) {
      f16x8 b = bR[t * 256];
      acc[1][t] = __builtin_amdgcn_mfma_f32_16x16x32_f16(a, b, acc[1][t], 0, 0, 0);
    }
  }

  const int rbase = (lane >> 4) * 4;
  #pragma unroll
  for (int t = 0; t < NT; ++t) {
    int col = t * 16 + col16;
    float bz = bias[col];
    #pragma unroll
    for (int j = 0; j < 4; ++j) {
      int row = row0 + rbase + j;
      if (row < n) {
        if constexpr (YMODE == 1) {
          __hip_fp8_e4m3 q(acc[0][t][j]);
          ((unsigned char*)Yv)[(size_t)row * DO + col] = q.__x;
        } else {
          ((__half*)Yv)[(size_t)row * DO + col] = __float2half_rn(acc[0][t][j]);
        }
        Z[(size_t)row * DO + col] = __float2half_rn(acc[1][t][j] + bz);
      }
    }
  }
}

// ---------------------------------------------------------------------------
// 6) SINGLE-PASS aggregation per layer over contiguous Y rows (128B/edge
// burst, edge_weights' proven access shape). 8 lanes/edge, 8 edges in
// flight, int4/lane. Reduce shfl_xor 8/16/32; epilogue lanes 0..7.
template <bool DO_BN, bool HALF_OUT, bool FP8Y>
__global__ __launch_bounds__(256) void agg_pass(
    const void* __restrict__ Ypv, const __half* __restrict__ Zb,
    const int* __restrict__ rowptr, const unsigned* __restrict__ csrp,
    const float* __restrict__ denom,
    const float* __restrict__ g, const float* __restrict__ bb,
    const float* __restrict__ mm, const float* __restrict__ vv,
    void* __restrict__ outv, int dofull, int n) {
  constexpr int CH = FP8Y ? 16 : 8;    // channels per lane (int4 worth)
  int wid  = (int)((blockIdx.x * blockDim.x + threadIdx.x) >> 6);
  int lane = threadIdx.x & 63;
  if (wid >= n) return;
  int grp = lane >> 3;     // edge slot 0..7
  int sub = lane & 7;      // channel slice 0..7
  int beg = rowptr[wid], end = rowptr[wid + 1];
  float inv = 1.0f / (denom[wid] + 1e-16f);

  float a[CH];
  #pragma unroll
  for (int k = 0; k < CH; ++k) a[k] = 0.0f;

  for (int base = beg; base < end; base += 64) {
    int m = min(64, end - base);
    unsigned pk = (lane < m) ? csrp[base + lane] : 0u;   // w=0 when inactive
    int iters = (m + 7) >> 3;
    #pragma unroll 4
    for (int q = 0; q < iters; ++q) {
      unsigned u = __shfl(pk, q * 8 + grp);
      int   s = (int)(u & 0xFFFFu);
      float w = __half2float(__ushort_as_half((unsigned short)(u >> 16)));
      if constexpr (FP8Y) {
        int4 raw = ((const int4*)((const unsigned char*)Ypv +
                                  (size_t)s * 128))[sub];
        unsigned ww[4] = {(unsigned)raw.x, (unsigned)raw.y,
                          (unsigned)raw.z, (unsigned)raw.w};
        #pragma unroll
        for (int wi = 0; wi < 4; ++wi) {
          f32x2 lo = __builtin_amdgcn_cvt_pk_f32_fp8(ww[wi], false);
          f32x2 hi = __builtin_amdgcn_cvt_pk_f32_fp8(ww[wi], true);
          a[wi * 4 + 0] = fmaf(w, lo[0], a[wi * 4 + 0]);
          a[wi * 4 + 1] = fmaf(w, lo[1], a[wi * 4 + 1]);
          a[wi * 4 + 2] = fmaf(w, hi[0], a[wi * 4 + 2]);
          a[wi * 4 + 3] = fmaf(w, hi[1], a[wi * 4 + 3]);
        }
      } else {
        int4 raw = ((const int4*)((const __half*)Ypv + (size_t)s * 64))[sub];
        const __half2* hh = (const __half2*)&raw;
        #pragma unroll
        for (int k = 0; k < 4; ++k) {
          float2 f = __half22float2(hh[k]);
          a[2 * k]     = fmaf(w, f.x, a[2 * k]);
          a[2 * k + 1] = fmaf(w, f.y, a[2 * k + 1]);
        }
      }
    }
  }
  #pragma unroll
  for (int off = 8; off <= 32; off <<= 1) {
    #pragma unroll
    for (int k = 0; k < CH; ++k) a[k] += __shfl_xor(a[k], off);
  }

  if (lane < 8) {
    int c = sub * CH;
    float o[CH];
    const int4* zp = (const int4*)(Zb + (size_t)wid * dofull + c);
    #pragma unroll
    for (int v = 0; v < CH / 8; ++v) {
      int4 zr = zp[v];
      const __half2* zh = (const __half2*)&zr;
      #pragma unroll
      for (int k = 0; k < 4; ++k) {
        float2 z = __half22float2(zh[k]);
        o[v * 8 + 2 * k]     = fmaf(a[v * 8 + 2 * k], inv, z.x);
        o[v * 8 + 2 * k + 1] = fmaf(a[v * 8 + 2 * k + 1], inv, z.y);
      }
    }
    if constexpr (DO_BN) {
      #pragma unroll
      for (int k = 0; k < CH; ++k) {
        float sc = g[c + k] * rsqrtf(vv[c + k] + BN_EPS);
        o[k] = fmaxf(fmaf(o[k] - mm[c + k], sc, bb[c + k]), 0.0f);
      }
    }
    if constexpr (HALF_OUT) {
      #pragma unroll
      for (int v = 0; v < CH / 8; ++v) {
        __half2 p0 = __floats2half2_rn(o[v * 8 + 0], o[v * 8 + 1]);
        __half2 p1 = __floats2half2_rn(o[v * 8 + 2], o[v * 8 + 3]);
        __half2 p2 = __floats2half2_rn(o[v * 8 + 4], o[v * 8 + 5]);
        __half2 p3 = __floats2half2_rn(o[v * 8 + 6], o[v * 8 + 7]);
        int4 pk4;
        pk4.x = *(int*)&p0; pk4.y = *(int*)&p1;
        pk4.z = *(int*)&p2; pk4.w = *(int*)&p3;
        ((int4*)((__half*)outv + (size_t)wid * dofull + c))[v] = pk4;
      }
    } else {
      float* op = (float*)outv + (size_t)wid * dofull + c;
      #pragma unroll
      for (int v = 0; v < CH / 4; ++v)
        ((float4*)op)[v] = make_float4(o[v * 4], o[v * 4 + 1],
                                       o[v * 4 + 2], o[v * 4 + 3]);
    }
  }
}

// ---------------------------------------------------------------------------
extern "C" void kernel_launch(void* const* d_in, const int* in_sizes, int n_in,
                              void* d_out, int out_size, void* d_ws, size_t ws_size,
                              hipStream_t stream) {
  const float* x   = (const float*)d_in[0];
  const int*   ei  = (const int*)d_in[1];
  const float* Wn0 = (const float*)d_in[2];
  const float* cn0 = (const float*)d_in[3];
  const float* Wr0 = (const float*)d_in[4];
  const float* cr0 = (const float*)d_in[5];
  const float* Wn1 = (const float*)d_in[6];
  const float* cn1 = (const float*)d_in[7];
  const float* Wr1 = (const float*)d_in[8];
  const float* cr1 = (const float*)d_in[9];
  const float* Wn2 = (const float*)d_in[10];
  const float* cn2 = (const float*)d_in[11];
  const float* Wr2 = (const float*)d_in[12];
  const float* cr2 = (const float*)d_in[13];
  const float* g0  = (const float*)d_in[14];
  const float* b0  = (const float*)d_in[15];
  const float* m0  = (const float*)d_in[16];
  const float* v0  = (const float*)d_in[17];
  const float* g1  = (const float*)d_in[18];
  const float* b1  = (const float*)d_in[19];
  const float* m1  = (const float*)d_in[20];
  const float* v1  = (const float*)d_in[21];

  const int* src = ei;
  const int* dst = ei + E_EDGES;

  char* p = (char*)d_ws;
  auto alloc = [&](size_t bytes) {
    char* r = p;
    p += (bytes + 255) & ~(size_t)255;
    return r;
  };
  __half*         P0      = (__half*)        alloc((size_t)N_NODES * 128 * 2);
  __half*         P1      = (__half*)        alloc((size_t)N_NODES * 128 * 2);
  __half*         A16     = (__half*)        alloc((size_t)N_NODES * 128 * 2);
  unsigned*       staging = (unsigned*)      alloc((size_t)NSB * NSUBL * SUBCAP * 4); // 8 MB
  int*            deg     = (int*)           alloc((size_t)N_NODES * 4);
  float*          denom   = (float*)         alloc((size_t)N_NODES * 4);
  int*            rowptr  = (int*)           alloc((size_t)(N_NODES + 1) * 4);
  int*            gcur    = (int*)           alloc((size_t)N_NODES * 4);
  int*            sbsum   = (int*)           alloc((size_t)NSB * 4);
  int*            sbbase  = (int*)           alloc((size_t)NSB * 4);
  int*            gc      = (int*)           alloc((size_t)(NSB * NSUBL * BSTR + 16) * 4);
  unsigned short* csrs16  = (unsigned short*)alloc((size_t)E_EDGES * 2);
  unsigned*       csrp    = (unsigned*)      alloc((size_t)E_EDGES * 4);
  __half*         WtN0    = (__half*)        alloc(128 * 128 * 2);
  __half*         WtR0    = (__half*)        alloc(128 * 128 * 2);
  __half*         WtN1    = (__half*)        alloc(128 * 128 * 2);
  __half*         WtR1    = (__half*)        alloc(128 * 128 * 2);
  __half*         WtN2    = (__half*)        alloc(64 * 128 * 2);
  __half*         WtR2    = (__half*)        alloc(64 * 128 * 2);
  float*          bias0   = (float*)         alloc(128 * 4);
  float*          bias1   = (float*)         alloc(128 * 4);
  float*          bias2   = (float*)         alloc(64 * 4);

  // xn8 (6.4 MB), fp8 Y rows (6.4 MB), and fp16 final Y rows (6.4 MB) all
  // live in P0 (sequential lifetimes).
  unsigned char* xn8 = (unsigned char*)P0;
  unsigned char* Y8  = (unsigned char*)P0;
  __half*        Yf  = P0;

  // overflow list aliases csrp (only written later by edge_weights)
  unsigned* ostage = (unsigned*)csrp;
  int*      ocnt   = gc + NSB * NSUBL * BSTR;   // covered by gc memset

  hipMemsetAsync(gc, 0, (size_t)(NSB * NSUBL * BSTR + 16) * 4, stream);

  const int node_grid = (N_NODES * 64 + 255) / 256;

  xn_norm<<<node_grid, 256, 0, stream>>>(x, xn8, N_NODES);
  prep_weights<<<320, 256, 0, stream>>>(Wn0, Wr0, Wn1, Wr1, Wn2, Wr2,
                                        cn0, cr0, cn1, cr1, cn2, cr2,
                                        WtN0, WtR0, WtN1, WtR1, WtN2, WtR2,
                                        bias0, bias1, bias2);
  scatter_sb<<<SCGRID, 256, 0, stream>>>(src, dst, gc, staging, ocnt, ostage, E_EDGES);
  hist_sb<<<NSB, 256, 0, stream>>>(staging, gc, deg, sbsum, N_NODES);
  overflow_deg<<<64, 256, 0, stream>>>(ostage, ocnt, deg, sbsum);
  scan_sb<<<1, 128, 0, stream>>>(sbsum, sbbase, rowptr, N_NODES);
  rowptr_sb<<<NSB, 256, 0, stream>>>(deg, sbbase, rowptr, N_NODES);
  place_sb<<<NSB, 256, 0, stream>>>(staging, gc, rowptr, csrs16, gcur, N_NODES);
  overflow_place<<<64, 256, 0, stream>>>(ostage, ocnt, gcur, csrs16);
  edge_weights<<<node_grid, 256, 0, stream>>>(xn8, rowptr, csrs16, csrp, denom, N_NODES);

  const int gemm_grid = (N_NODES + 63) / 64;

  // layer 0: H = x (f32), Y -> fp8 128-ch rows (over xn8, dead), out -> A16
  gemm_dual_mfma<128, float, 1><<<gemm_grid, 256, 0, stream>>>(
      x, WtN0, WtR0, bias0, Y8, P1, N_NODES);
  agg_pass<true, true, true><<<node_grid, 256, 0, stream>>>(
      Y8, P1, rowptr, csrp, denom, g0, b0, m0, v0, A16, 128, N_NODES);

  // layer 1: H = A16 (fp16)
  gemm_dual_mfma<128, __half, 1><<<gemm_grid, 256, 0, stream>>>(
      A16, WtN1, WtR1, bias1, Y8, P1, N_NODES);
  agg_pass<true, true, true><<<node_grid, 256, 0, stream>>>(
      Y8, P1, rowptr, csrp, denom, g1, b1, m1, v1, A16, 128, N_NODES);

  // layer 2 (64-wide): Y -> fp16 64-ch rows, out -> d_out (f32)
  gemm_dual_mfma<64, __half, 0><<<gemm_grid, 256, 0, stream>>>(
      A16, WtN2, WtR2, bias2, Yf, P1, N_NODES);
  agg_pass<false, false, false><<<node_grid, 256, 0, stream>>>(
      Yf, P1, rowptr, csrp, denom,
      nullptr, nullptr, nullptr, nullptr, d_out, 64, N_NODES);
}

// Round 22
// 357.287 us; speedup vs baseline: 1.7450x; 1.0055x over previous
//
#include <hip/hip_runtime.h>
#include <hip/hip_fp16.h>
#include <hip/hip_fp8.h>
#include <math.h>
#include <type_traits>

#define N_NODES 50000
#define E_EDGES 1600000
#define TAU     0.5f
#define BN_EPS  1e-5f
#define SBSH    9                        // 512 dst nodes per super-bucket
#define NSB     ((N_NODES + 511) >> 9)   // 98 super-buckets
#define NSUBL   8                        // staging sub-lists (spread cursor LINES)
#define SUBCAP  2560                     // entries per sub-list (mean 2048 + >10 sigma)
#define BINCAP  48                       // LDS bin capacity (mean 10.4, +11 sigma)
#define EPB     1024                     // edges per scatter block
#define SCGRID  ((E_EDGES + EPB - 1) / EPB)
#define BSTR    16                       // cursor stride in ints (64B/line)

typedef _Float16 f16x8 __attribute__((ext_vector_type(8)));
typedef float    f32x4 __attribute__((ext_vector_type(4)));
typedef float    f32x2 __attribute__((ext_vector_type(2)));

// packed dual-FMA on f32 pairs (v_pk_fma_f32, gfx90a+): d = a*b + c
__device__ __forceinline__ f32x2 pk_fma(f32x2 a, f32x2 b, f32x2 c) {
  f32x2 d;
  asm volatile("v_pk_fma_f32 %0, %1, %2, %3"
               : "=v"(d) : "v"(a), "v"(b), "v"(c));
  return d;
}

// dot of 16 fp8 pairs held in two int4 registers (OCP e4m3, HW cvt)
__device__ __forceinline__ float dot16_fp8(int4 a, int4 b) {
  unsigned wa[4] = {(unsigned)a.x, (unsigned)a.y, (unsigned)a.z, (unsigned)a.w};
  unsigned wb[4] = {(unsigned)b.x, (unsigned)b.y, (unsigned)b.z, (unsigned)b.w};
  float acc = 0.0f;
  #pragma unroll
  for (int i = 0; i < 4; ++i) {
    f32x2 alo = __builtin_amdgcn_cvt_pk_f32_fp8(wa[i], false);
    f32x2 ahi = __builtin_amdgcn_cvt_pk_f32_fp8(wa[i], true);
    f32x2 blo = __builtin_amdgcn_cvt_pk_f32_fp8(wb[i], false);
    f32x2 bhi = __builtin_amdgcn_cvt_pk_f32_fp8(wb[i], true);
    acc = fmaf(alo[0], blo[0], acc);
    acc = fmaf(alo[1], blo[1], acc);
    acc = fmaf(ahi[0], bhi[0], acc);
    acc = fmaf(ahi[1], bhi[1], acc);
  }
  return acc;
}

// ---------------------------------------------------------------------------
// 1) normalized FP8 features: xn8[i] = e4m3( x_i / (||x_i|| + 1e-12) )
__global__ __launch_bounds__(256) void xn_norm(
    const float* __restrict__ x, unsigned char* __restrict__ xn8, int n) {
  int wid  = (int)((blockIdx.x * blockDim.x + threadIdx.x) >> 6);
  int lane = threadIdx.x & 63;
  if (wid >= n) return;
  float2 v = ((const float2*)(x + (size_t)wid * 128))[lane];
  float s = v.x * v.x + v.y * v.y;
  #pragma unroll
  for (int off = 32; off; off >>= 1) s += __shfl_xor(s, off);
  float inv = 1.0f / (sqrtf(s) + 1e-12f);
  __hip_fp8_e4m3 q0(v.x * inv), q1(v.y * inv);
  uchar2 pk;
  pk.x = q0.__x; pk.y = q1.__x;
  ((uchar2*)(xn8 + (size_t)wid * 128))[lane] = pk;
}

// ---------------------------------------------------------------------------
// 2a) LDS-binned scatter (unchanged)
__global__ __launch_bounds__(256) void scatter_sb(
    const int* __restrict__ src, const int* __restrict__ dst,
    int* __restrict__ gc, unsigned* __restrict__ staging,
    int* __restrict__ ocnt, unsigned* __restrict__ ostage, int e) {
  __shared__ unsigned bins[NSB][BINCAP];
  __shared__ int bcount[NSB];
  const int tid  = threadIdx.x;
  const int wv   = tid >> 6;
  const int lane = tid & 63;
  const int sl   = blockIdx.x & (NSUBL - 1);
  for (int i = tid; i < NSB; i += 256) bcount[i] = 0;
  __syncthreads();

  int base = blockIdx.x * EPB;
  int bend = min(base + EPB, e);
  for (int i = base + tid; i < bend; i += 256) {
    int d = dst[i], s = src[i];
    int sb = d >> SBSH;
    int pos = atomicAdd(&bcount[sb], 1);
    if (pos < BINCAP) {
      bins[sb][pos] = (unsigned)s | ((unsigned)(d & 511) << 16);
    } else {
      int op = atomicAdd(ocnt, 1);
      ostage[op] = (unsigned)s | ((unsigned)d << 16);   // full dst
    }
  }
  __syncthreads();

  for (int sb = wv; sb < NSB; sb += 4) {
    int cnt = min(bcount[sb], BINCAP);
    if (cnt > 0) {
      int cell = sb * NSUBL + sl;
      int gbase = 0;
      if (lane == 0) gbase = atomicAdd(&gc[cell * BSTR], cnt);
      gbase = __shfl(gbase, 0);
      if (gbase + cnt <= SUBCAP) {
        if (lane < cnt)
          staging[(size_t)cell * SUBCAP + gbase + lane] = bins[sb][lane];
      } else if (lane < cnt) {
        unsigned u = bins[sb][lane];
        int op = atomicAdd(ocnt, 1);
        ostage[op] = (u & 0xFFFFu) | ((unsigned)((sb << SBSH) | (u >> 16)) << 16);
      }
    }
  }
}

// ---------------------------------------------------------------------------
// 2b) per-SB LDS histogram over the 8 sub-lists -> deg + SB total
__global__ __launch_bounds__(256) void hist_sb(
    const unsigned* __restrict__ staging, const int* __restrict__ gc,
    int* __restrict__ deg, int* __restrict__ sbsum, int n) {
  __shared__ int h[512];
  __shared__ int wt[4];
  int sb = blockIdx.x;
  for (int i = threadIdx.x; i < 512; i += 256) h[i] = 0;
  __syncthreads();
  for (int s = 0; s < NSUBL; ++s) {
    int cell = sb * NSUBL + s;
    int m = min(gc[cell * BSTR], SUBCAP);
    for (int i = threadIdx.x; i < m; i += 256)
      atomicAdd(&h[(staging[(size_t)cell * SUBCAP + i] >> 16) & 511], 1);
  }
  __syncthreads();
  int d0 = sb << SBSH;
  for (int i = threadIdx.x; i < 512; i += 256)
    if (d0 + i < n) deg[d0 + i] = h[i];
  int t = h[threadIdx.x] + h[threadIdx.x + 256];
  #pragma unroll
  for (int off = 32; off; off >>= 1) t += __shfl_xor(t, off);
  if ((threadIdx.x & 63) == 0) wt[threadIdx.x >> 6] = t;
  __syncthreads();
  if (threadIdx.x == 0) sbsum[sb] = wt[0] + wt[1] + wt[2] + wt[3];
}

// ---------------------------------------------------------------------------
// 2b') overflow patch (no-op when ocnt==0)
__global__ __launch_bounds__(256) void overflow_deg(
    const unsigned* __restrict__ ostage, const int* __restrict__ ocnt,
    int* __restrict__ deg, int* __restrict__ sbsum) {
  int m = *ocnt;
  for (int i = blockIdx.x * blockDim.x + threadIdx.x; i < m;
       i += gridDim.x * blockDim.x) {
    int d = (int)(ostage[i] >> 16);
    atomicAdd(&deg[d], 1);
    atomicAdd(&sbsum[d >> SBSH], 1);
  }
}

// ---------------------------------------------------------------------------
// 3a) exclusive scan over the 98 SB sums
__global__ void scan_sb(const int* __restrict__ sbsum, int* __restrict__ sbbase,
                        int* __restrict__ rowptr, int n) {
  __shared__ int part[128];
  int t = (int)threadIdx.x;
  int v = (t < NSB) ? sbsum[t] : 0;
  part[t] = v;
  __syncthreads();
  for (int off = 1; off < 128; off <<= 1) {
    int u = (t >= off) ? part[t - off] : 0;
    __syncthreads();
    part[t] += u;
    __syncthreads();
  }
  if (t < NSB) sbbase[t] = part[t] - v;
  if (t == 127) rowptr[n] = part[127];
}

// ---------------------------------------------------------------------------
// 3b) rowptr within SB: 512-element block scan (2 per thread)
__global__ __launch_bounds__(256) void rowptr_sb(
    const int* __restrict__ deg, const int* __restrict__ sbbase,
    int* __restrict__ rowptr, int n) {
  __shared__ int part[256];
  int sb = blockIdx.x;
  int d0 = sb << SBSH;
  int t = (int)threadIdx.x;
  int e0 = d0 + 2 * t;
  int v0 = (e0 < n) ? deg[e0] : 0;
  int v1 = (e0 + 1 < n) ? deg[e0 + 1] : 0;
  int s = v0 + v1;
  part[t] = s;
  __syncthreads();
  for (int off = 1; off < 256; off <<= 1) {
    int u = (t >= off) ? part[t - off] : 0;
    __syncthreads();
    part[t] += u;
    __syncthreads();
  }
  int ex = part[t] - s + sbbase[sb];
  if (e0 < n) rowptr[e0] = ex;
  if (e0 + 1 < n) rowptr[e0 + 1] = ex + v0;
}

// ---------------------------------------------------------------------------
// 2c) placement (unchanged)
__global__ __launch_bounds__(256) void place_sb(
    const unsigned* __restrict__ staging, const int* __restrict__ gc,
    const int* __restrict__ rowptr, unsigned short* __restrict__ csr16,
    int* __restrict__ gcur, int n) {
  __shared__ int cur[512];
  int sb = blockIdx.x;
  int d0 = sb << SBSH;
  for (int i = threadIdx.x; i < 512; i += 256)
    cur[i] = (d0 + i < n) ? rowptr[d0 + i] : 0;
  __syncthreads();
  for (int s = 0; s < NSUBL; ++s) {
    int cell = sb * NSUBL + s;
    int m = min(gc[cell * BSTR], SUBCAP);
    for (int i = threadIdx.x; i < m; i += 256) {
      unsigned u = staging[(size_t)cell * SUBCAP + i];
      int j = (u >> 16) & 511;
      int pos = atomicAdd(&cur[j], 1);
      csr16[pos] = (unsigned short)(u & 0xFFFFu);
    }
  }
  __syncthreads();
  for (int i = threadIdx.x; i < 512; i += 256)
    if (d0 + i < n) gcur[d0 + i] = cur[i];
}

// ---------------------------------------------------------------------------
// 2c') overflow placement (no-op when ocnt==0)
__global__ __launch_bounds__(256) void overflow_place(
    const unsigned* __restrict__ ostage, const int* __restrict__ ocnt,
    int* __restrict__ gcur, unsigned short* __restrict__ csr16) {
  int m = *ocnt;
  for (int i = blockIdx.x * blockDim.x + threadIdx.x; i < m;
       i += gridDim.x * blockDim.x) {
    unsigned u = ostage[i];
    int d = (int)(u >> 16);
    int pos = atomicAdd(&gcur[d], 1);
    csr16[pos] = (unsigned short)(u & 0xFFFFu);
  }
}

// ---------------------------------------------------------------------------
// 4) edge weights, dst-ordered, FP8 features (unchanged)
__global__ __launch_bounds__(256) void edge_weights(
    const unsigned char* __restrict__ xn8, const int* __restrict__ rowptr,
    const unsigned short* __restrict__ csr_src16,
    unsigned* __restrict__ csrp, float* __restrict__ denom, int n) {
  int wid  = (int)((blockIdx.x * blockDim.x + threadIdx.x) >> 6);
  int lane = threadIdx.x & 63;
  if (wid >= n) return;
  int grp = lane >> 3;       // edge slot 0..7
  int sub = lane & 7;        // 16-dim slice
  int beg = rowptr[wid], end = rowptr[wid + 1];
  int4 xdv = ((const int4*)(xn8 + (size_t)wid * 128))[sub];
  float wsum = 0.0f;

  for (int base = beg; base < end; base += 64) {
    int m = min(64, end - base);
    int sv = (lane < m) ? (int)csr_src16[base + lane] : 0;
    int iters = (m + 7) >> 3;
    #pragma unroll 2
    for (int q = 0; q < iters; ++q) {
      int ei = q * 8 + grp;
      int s = __shfl(sv, ei);
      int4 xsv = ((const int4*)(xn8 + (size_t)s * 128))[sub];
      float dp = dot16_fp8(xsv, xdv);
      dp += __shfl_xor(dp, 1);
      dp += __shfl_xor(dp, 2);
      dp += __shfl_xor(dp, 4);
      bool valid = ei < m;
      float w = valid ? __expf(dp * (1.0f / TAU)) : 0.0f;
      wsum += w;
      if (valid && sub == 0) {
        unsigned w16 = (unsigned)__half_as_ushort(__float2half_rn(w));
        csrp[base + ei] = (unsigned)s | (w16 << 16);
      }
    }
  }
  wsum += __shfl_xor(wsum, 8);
  wsum += __shfl_xor(wsum, 16);
  wsum += __shfl_xor(wsum, 32);
  if (lane == 0) denom[wid] = wsum;
}

// ---------------------------------------------------------------------------
// 5a) weight prepack in MFMA fragment order (unchanged)
__global__ __launch_bounds__(256) void prep_weights(
    const float* __restrict__ Wn0, const float* __restrict__ Wr0,
    const float* __restrict__ Wn1, const float* __restrict__ Wr1,
    const float* __restrict__ Wn2, const float* __restrict__ Wr2,
    const float* __restrict__ cn0, const float* __restrict__ cr0,
    const float* __restrict__ cn1, const float* __restrict__ cr1,
    const float* __restrict__ cn2, const float* __restrict__ cr2,
    __half* __restrict__ WtN0, __half* __restrict__ WtR0,
    __half* __restrict__ WtN1, __half* __restrict__ WtR1,
    __half* __restrict__ WtN2, __half* __restrict__ WtR2,
    float* __restrict__ bias0, float* __restrict__ bias1,
    float* __restrict__ bias2) {
  int i = blockIdx.x * blockDim.x + threadIdx.x;
  const float* Ws[6] = {Wn0, Wr0, Wn1, Wr1, Wn2, Wr2};
  __half*     Wts[6] = {WtN0, WtR0, WtN1, WtR1, WtN2, WtR2};
  int seg = -1, off = 0;
  if (i < 65536)        { seg = i >> 14;               off = i & 16383; }
  else if (i < 81920)   { int j = i - 65536; seg = 4 + (j >> 13); off = j & 8191; }
  if (seg >= 0) {
    int DO = (seg < 4) ? 128 : 64;
    int c = off >> 7, k = off & 127;
    int t = c >> 4, kc = k >> 5, kgrp = (k >> 3) & 3, j = k & 7;
    int lane = (c & 15) | (kgrp << 4);
    int idx = (((t * 4 + kc) * 64 + lane) << 3) + j;
    Wts[seg][idx] = __float2half_rn(Ws[seg][(size_t)k * DO + c]);
  }
  if (i < 128) { bias0[i] = cn0[i] + cr0[i]; bias1[i] = cn1[i] + cr1[i]; }
  if (i < 64)  { bias2[i] = cn2[i] + cr2[i]; }
}

// ---------------------------------------------------------------------------
// 5b) dual MFMA GEMM (unchanged from R21)
template <int DO, typename TIN, int YMODE>
__global__ __launch_bounds__(256) void gemm_dual_mfma(
    const TIN* __restrict__ H, const __half* __restrict__ WfN,
    const __half* __restrict__ WfR, const float* __restrict__ bias,
    void* __restrict__ Yv, __half* __restrict__ Z, int n) {
  constexpr int NT = DO / 16;
  const int lane  = threadIdx.x & 63;
  const int w     = threadIdx.x >> 6;
  const int row0  = blockIdx.x * 64 + w * 16;
  const int col16 = lane & 15;
  const int kgrp  = (lane >> 4) * 8;
  const size_t arow = (size_t)min(row0 + col16, n - 1);

  f32x4 acc[2][NT];
  #pragma unroll
  for (int m = 0; m < 2; ++m)
    #pragma unroll
    for (int t = 0; t < NT; ++t) acc[m][t] = (f32x4){0.f, 0.f, 0.f, 0.f};

  #pragma unroll
  for (int kc = 0; kc < 4; ++kc) {
    f16x8 a;
    if constexpr (std::is_same<TIN, float>::value) {
      const float* hp = H + arow * 128 + kc * 32 + kgrp;
      float4 f0 = *(const float4*)hp;
      float4 f1 = *(const float4*)(hp + 4);
      a[0] = (_Float16)f0.x; a[1] = (_Float16)f0.y;
      a[2] = (_Float16)f0.z; a[3] = (_Float16)f0.w;
      a[4] = (_Float16)f1.x; a[5] = (_Float16)f1.y;
      a[6] = (_Float16)f1.z; a[7] = (_Float16)f1.w;
    } else {
      a = *(const f16x8*)(H + arow * 128 + kc * 32 + kgrp);
    }
    const f16x8* bN = (const f16x8*)(WfN + ((size_t)(kc * 64 + lane) << 3));
    const f16x8* bR = (const f16x8*)(WfR + ((size_t)(kc * 64 + lane) << 3));
    #pragma unroll
    for (int t = 0; t < NT; ++t) {
      f16x8 b = bN[t * 256];
      acc[0][t] = __builtin_amdgcn_mfma_f32_16x16x32_f16(a, b, acc[0][t], 0, 0, 0);
    }
    #pragma unroll
    for (int t = 0; t < NT; ++t) {
      f16x8 b = bR[t * 256];
      acc[1][t] = __builtin_amdgcn_mfma_f32_16x16x32_f16(a, b, acc[1][t], 0, 0, 0);
    }
  }

  const int rbase = (lane >> 4) * 4;
  #pragma unroll
  for (int t = 0; t < NT; ++t) {
    int col = t * 16 + col16;
    float bz = bias[col];
    #pragma unroll
    for (int j = 0; j < 4; ++j) {
      int row = row0 + rbase + j;
      if (row < n) {
        if constexpr (YMODE == 1) {
          __hip_fp8_e4m3 q(acc[0][t][j]);
          ((unsigned char*)Yv)[(size_t)row * DO + col] = q.__x;
        } else {
          ((__half*)Yv)[(size_t)row * DO + col] = __float2half_rn(acc[0][t][j]);
        }
        Z[(size_t)row * DO + col] = __float2half_rn(acc[1][t][j] + bz);
      }
    }
  }
}

// ---------------------------------------------------------------------------
// 6) SINGLE-PASS aggregation per layer over contiguous Y rows. FMA work done
// with v_pk_fma_f32 (2 ch/instruction): fp8 path 8 cvt + 8 pk_fma per edge
// slice (was 8 cvt + 16 fma -> issue-bound at 55us).
template <bool DO_BN, bool HALF_OUT, bool FP8Y>
__global__ __launch_bounds__(256) void agg_pass(
    const void* __restrict__ Ypv, const __half* __restrict__ Zb,
    const int* __restrict__ rowptr, const unsigned* __restrict__ csrp,
    const float* __restrict__ denom,
    const float* __restrict__ g, const float* __restrict__ bb,
    const float* __restrict__ mm, const float* __restrict__ vv,
    void* __restrict__ outv, int dofull, int n) {
  constexpr int CH  = FP8Y ? 16 : 8;   // channels per lane
  constexpr int CH2 = CH / 2;          // f32x2 accumulators
  int wid  = (int)((blockIdx.x * blockDim.x + threadIdx.x) >> 6);
  int lane = threadIdx.x & 63;
  if (wid >= n) return;
  int grp = lane >> 3;     // edge slot 0..7
  int sub = lane & 7;      // channel slice 0..7
  int beg = rowptr[wid], end = rowptr[wid + 1];
  float inv = 1.0f / (denom[wid] + 1e-16f);

  f32x2 a2[CH2];
  #pragma unroll
  for (int k = 0; k < CH2; ++k) a2[k] = (f32x2){0.f, 0.f};

  for (int base = beg; base < end; base += 64) {
    int m = min(64, end - base);
    unsigned pk = (lane < m) ? csrp[base + lane] : 0u;   // w=0 when inactive
    int iters = (m + 7) >> 3;
    #pragma unroll 4
    for (int q = 0; q < iters; ++q) {
      unsigned u = __shfl(pk, q * 8 + grp);
      int   s = (int)(u & 0xFFFFu);
      float w = __half2float(__ushort_as_half((unsigned short)(u >> 16)));
      f32x2 w2 = {w, w};
      if constexpr (FP8Y) {
        int4 raw = ((const int4*)((const unsigned char*)Ypv +
                                  (size_t)s * 128))[sub];
        unsigned ww[4] = {(unsigned)raw.x, (unsigned)raw.y,
                          (unsigned)raw.z, (unsigned)raw.w};
        #pragma unroll
        for (int wi = 0; wi < 4; ++wi) {
          f32x2 lo = __builtin_amdgcn_cvt_pk_f32_fp8(ww[wi], false);
          f32x2 hi = __builtin_amdgcn_cvt_pk_f32_fp8(ww[wi], true);
          a2[wi * 2 + 0] = pk_fma(w2, lo, a2[wi * 2 + 0]);
          a2[wi * 2 + 1] = pk_fma(w2, hi, a2[wi * 2 + 1]);
        }
      } else {
        int4 raw = ((const int4*)((const __half*)Ypv + (size_t)s * 64))[sub];
        const __half2* hh = (const __half2*)&raw;
        #pragma unroll
        for (int k = 0; k < 4; ++k) {
          float2 f = __half22float2(hh[k]);
          f32x2 fv = {f.x, f.y};
          a2[k] = pk_fma(w2, fv, a2[k]);
        }
      }
    }
  }
  #pragma unroll
  for (int off = 8; off <= 32; off <<= 1) {
    #pragma unroll
    for (int k = 0; k < CH2; ++k) {
      a2[k][0] += __shfl_xor(a2[k][0], off);
      a2[k][1] += __shfl_xor(a2[k][1], off);
    }
  }

  if (lane < 8) {
    int c = sub * CH;
    float o[CH];
    const int4* zp = (const int4*)(Zb + (size_t)wid * dofull + c);
    #pragma unroll
    for (int v = 0; v < CH / 8; ++v) {
      int4 zr = zp[v];
      const __half2* zh = (const __half2*)&zr;
      #pragma unroll
      for (int k = 0; k < 4; ++k) {
        float2 z = __half22float2(zh[k]);
        o[v * 8 + 2 * k]     = fmaf(a2[v * 4 + k][0], inv, z.x);
        o[v * 8 + 2 * k + 1] = fmaf(a2[v * 4 + k][1], inv, z.y);
      }
    }
    if constexpr (DO_BN) {
      #pragma unroll
      for (int k = 0; k < CH; ++k) {
        float sc = g[c + k] * rsqrtf(vv[c + k] + BN_EPS);
        o[k] = fmaxf(fmaf(o[k] - mm[c + k], sc, bb[c + k]), 0.0f);
      }
    }
    if constexpr (HALF_OUT) {
      #pragma unroll
      for (int v = 0; v < CH / 8; ++v) {
        __half2 p0 = __floats2half2_rn(o[v * 8 + 0], o[v * 8 + 1]);
        __half2 p1 = __floats2half2_rn(o[v * 8 + 2], o[v * 8 + 3]);
        __half2 p2 = __floats2half2_rn(o[v * 8 + 4], o[v * 8 + 5]);
        __half2 p3 = __floats2half2_rn(o[v * 8 + 6], o[v * 8 + 7]);
        int4 pk4;
        pk4.x = *(int*)&p0; pk4.y = *(int*)&p1;
        pk4.z = *(int*)&p2; pk4.w = *(int*)&p3;
        ((int4*)((__half*)outv + (size_t)wid * dofull + c))[v] = pk4;
      }
    } else {
      float* op = (float*)outv + (size_t)wid * dofull + c;
      #pragma unroll
      for (int v = 0; v < CH / 4; ++v)
        ((float4*)op)[v] = make_float4(o[v * 4], o[v * 4 + 1],
                                       o[v * 4 + 2], o[v * 4 + 3]);
    }
  }
}

// ---------------------------------------------------------------------------
extern "C" void kernel_launch(void* const* d_in, const int* in_sizes, int n_in,
                              void* d_out, int out_size, void* d_ws, size_t ws_size,
                              hipStream_t stream) {
  const float* x   = (const float*)d_in[0];
  const int*   ei  = (const int*)d_in[1];
  const float* Wn0 = (const float*)d_in[2];
  const float* cn0 = (const float*)d_in[3];
  const float* Wr0 = (const float*)d_in[4];
  const float* cr0 = (const float*)d_in[5];
  const float* Wn1 = (const float*)d_in[6];
  const float* cn1 = (const float*)d_in[7];
  const float* Wr1 = (const float*)d_in[8];
  const float* cr1 = (const float*)d_in[9];
  const float* Wn2 = (const float*)d_in[10];
  const float* cn2 = (const float*)d_in[11];
  const float* Wr2 = (const float*)d_in[12];
  const float* cr2 = (const float*)d_in[13];
  const float* g0  = (const float*)d_in[14];
  const float* b0  = (const float*)d_in[15];
  const float* m0  = (const float*)d_in[16];
  const float* v0  = (const float*)d_in[17];
  const float* g1  = (const float*)d_in[18];
  const float* b1  = (const float*)d_in[19];
  const float* m1  = (const float*)d_in[20];
  const float* v1  = (const float*)d_in[21];

  const int* src = ei;
  const int* dst = ei + E_EDGES;

  char* p = (char*)d_ws;
  auto alloc = [&](size_t bytes) {
    char* r = p;
    p += (bytes + 255) & ~(size_t)255;
    return r;
  };
  __half*         P0      = (__half*)        alloc((size_t)N_NODES * 128 * 2);
  __half*         P1      = (__half*)        alloc((size_t)N_NODES * 128 * 2);
  __half*         A16     = (__half*)        alloc((size_t)N_NODES * 128 * 2);
  unsigned*       staging = (unsigned*)      alloc((size_t)NSB * NSUBL * SUBCAP * 4); // 8 MB
  int*            deg     = (int*)           alloc((size_t)N_NODES * 4);
  float*          denom   = (float*)         alloc((size_t)N_NODES * 4);
  int*            rowptr  = (int*)           alloc((size_t)(N_NODES + 1) * 4);
  int*            gcur    = (int*)           alloc((size_t)N_NODES * 4);
  int*            sbsum   = (int*)           alloc((size_t)NSB * 4);
  int*            sbbase  = (int*)           alloc((size_t)NSB * 4);
  int*            gc      = (int*)           alloc((size_t)(NSB * NSUBL * BSTR + 16) * 4);
  unsigned short* csrs16  = (unsigned short*)alloc((size_t)E_EDGES * 2);
  unsigned*       csrp    = (unsigned*)      alloc((size_t)E_EDGES * 4);
  __half*         WtN0    = (__half*)        alloc(128 * 128 * 2);
  __half*         WtR0    = (__half*)        alloc(128 * 128 * 2);
  __half*         WtN1    = (__half*)        alloc(128 * 128 * 2);
  __half*         WtR1    = (__half*)        alloc(128 * 128 * 2);
  __half*         WtN2    = (__half*)        alloc(64 * 128 * 2);
  __half*         WtR2    = (__half*)        alloc(64 * 128 * 2);
  float*          bias0   = (float*)         alloc(128 * 4);
  float*          bias1   = (float*)         alloc(128 * 4);
  float*          bias2   = (float*)         alloc(64 * 4);

  // xn8 (6.4 MB), fp8 Y rows (6.4 MB), fp16 final Y rows (6.4 MB) all live
  // in P0 (sequential lifetimes).
  unsigned char* xn8 = (unsigned char*)P0;
  unsigned char* Y8  = (unsigned char*)P0;
  __half*        Yf  = P0;

  // overflow list aliases csrp (only written later by edge_weights)
  unsigned* ostage = (unsigned*)csrp;
  int*      ocnt   = gc + NSB * NSUBL * BSTR;   // covered by gc memset

  hipMemsetAsync(gc, 0, (size_t)(NSB * NSUBL * BSTR + 16) * 4, stream);

  const int node_grid = (N_NODES * 64 + 255) / 256;

  xn_norm<<<node_grid, 256, 0, stream>>>(x, xn8, N_NODES);
  prep_weights<<<320, 256, 0, stream>>>(Wn0, Wr0, Wn1, Wr1, Wn2, Wr2,
                                        cn0, cr0, cn1, cr1, cn2, cr2,
                                        WtN0, WtR0, WtN1, WtR1, WtN2, WtR2,
                                        bias0, bias1, bias2);
  scatter_sb<<<SCGRID, 256, 0, stream>>>(src, dst, gc, staging, ocnt, ostage, E_EDGES);
  hist_sb<<<NSB, 256, 0, stream>>>(staging, gc, deg, sbsum, N_NODES);
  overflow_deg<<<64, 256, 0, stream>>>(ostage, ocnt, deg, sbsum);
  scan_sb<<<1, 128, 0, stream>>>(sbsum, sbbase, rowptr, N_NODES);
  rowptr_sb<<<NSB, 256, 0, stream>>>(deg, sbbase, rowptr, N_NODES);
  place_sb<<<NSB, 256, 0, stream>>>(staging, gc, rowptr, csrs16, gcur, N_NODES);
  overflow_place<<<64, 256, 0, stream>>>(ostage, ocnt, gcur, csrs16);
  edge_weights<<<node_grid, 256, 0, stream>>>(xn8, rowptr, csrs16, csrp, denom, N_NODES);

  const int gemm_grid = (N_NODES + 63) / 64;

  // layer 0: H = x (f32), Y -> fp8 128-ch rows (over xn8, dead), out -> A16
  gemm_dual_mfma<128, float, 1><<<gemm_grid, 256, 0, stream>>>(
      x, WtN0, WtR0, bias0, Y8, P1, N_NODES);
  agg_pass<true, true, true><<<node_grid, 256, 0, stream>>>(
      Y8, P1, rowptr, csrp, denom, g0, b0, m0, v0, A16, 128, N_NODES);

  // layer 1: H = A16 (fp16)
  gemm_dual_mfma<128, __half, 1><<<gemm_grid, 256, 0, stream>>>(
      A16, WtN1, WtR1, bias1, Y8, P1, N_NODES);
  agg_pass<true, true, true><<<node_grid, 256, 0, stream>>>(
      Y8, P1, rowptr, csrp, denom, g1, b1, m1, v1, A16, 128, N_NODES);

  // layer 2 (64-wide): Y -> fp16 64-ch rows, out -> d_out (f32)
  gemm_dual_mfma<64, __half, 0><<<gemm_grid, 256, 0, stream>>>(
      A16, WtN2, WtR2, bias2, Yf, P1, N_NODES);
  agg_pass<false, false, false><<<node_grid, 256, 0, stream>>>(
      Yf, P1, rowptr, csrp, denom,
      nullptr, nullptr, nullptr, nullptr, d_out, 64, N_NODES);
}

// Round 23
// 350.416 us; speedup vs baseline: 1.7792x; 1.0196x over previous
//
#include <hip/hip_runtime.h>
#include <hip/hip_fp16.h>
#include <hip/hip_fp8.h>
#include <math.h>
#include <type_traits>

#define N_NODES 50000
#define E_EDGES 1600000
#define TAU     0.5f
#define BN_EPS  1e-5f
#define SBSH    9                        // 512 dst nodes per super-bucket
#define NSB     ((N_NODES + 511) >> 9)   // 98 super-buckets
#define NSUBL   8                        // staging sub-lists (spread cursor LINES)
#define SUBCAP  2560                     // entries per sub-list (mean 2048 + >10 sigma)
#define BINCAP  48                       // LDS bin capacity (mean 10.4, +11 sigma)
#define EPB     1024                     // edges per scatter block
#define SCGRID  ((E_EDGES + EPB - 1) / EPB)
#define BSTR    16                       // cursor stride in ints (64B/line)

typedef _Float16 f16x8 __attribute__((ext_vector_type(8)));
typedef float    f32x4 __attribute__((ext_vector_type(4)));
typedef float    f32x2 __attribute__((ext_vector_type(2)));

// packed dual-FMA on f32 pairs (v_pk_fma_f32, gfx90a+): d = a*b + c
__device__ __forceinline__ f32x2 pk_fma(f32x2 a, f32x2 b, f32x2 c) {
  f32x2 d;
  asm volatile("v_pk_fma_f32 %0, %1, %2, %3"
               : "=v"(d) : "v"(a), "v"(b), "v"(c));
  return d;
}

// dot of 16 fp8 pairs held in two int4 registers (OCP e4m3, HW cvt)
__device__ __forceinline__ float dot16_fp8(int4 a, int4 b) {
  unsigned wa[4] = {(unsigned)a.x, (unsigned)a.y, (unsigned)a.z, (unsigned)a.w};
  unsigned wb[4] = {(unsigned)b.x, (unsigned)b.y, (unsigned)b.z, (unsigned)b.w};
  float acc = 0.0f;
  #pragma unroll
  for (int i = 0; i < 4; ++i) {
    f32x2 alo = __builtin_amdgcn_cvt_pk_f32_fp8(wa[i], false);
    f32x2 ahi = __builtin_amdgcn_cvt_pk_f32_fp8(wa[i], true);
    f32x2 blo = __builtin_amdgcn_cvt_pk_f32_fp8(wb[i], false);
    f32x2 bhi = __builtin_amdgcn_cvt_pk_f32_fp8(wb[i], true);
    acc = fmaf(alo[0], blo[0], acc);
    acc = fmaf(alo[1], blo[1], acc);
    acc = fmaf(ahi[0], bhi[0], acc);
    acc = fmaf(ahi[1], bhi[1], acc);
  }
  return acc;
}

// ---------------------------------------------------------------------------
// 1) normalized FP8 features: xn8[i] = e4m3( x_i / (||x_i|| + 1e-12) )
__global__ __launch_bounds__(256) void xn_norm(
    const float* __restrict__ x, unsigned char* __restrict__ xn8, int n) {
  int wid  = (int)((blockIdx.x * blockDim.x + threadIdx.x) >> 6);
  int lane = threadIdx.x & 63;
  if (wid >= n) return;
  float2 v = ((const float2*)(x + (size_t)wid * 128))[lane];
  float s = v.x * v.x + v.y * v.y;
  #pragma unroll
  for (int off = 32; off; off >>= 1) s += __shfl_xor(s, off);
  float inv = 1.0f / (sqrtf(s) + 1e-12f);
  __hip_fp8_e4m3 q0(v.x * inv), q1(v.y * inv);
  uchar2 pk;
  pk.x = q0.__x; pk.y = q1.__x;
  ((uchar2*)(xn8 + (size_t)wid * 128))[lane] = pk;
}

// ---------------------------------------------------------------------------
// 2a) LDS-binned scatter (unchanged)
__global__ __launch_bounds__(256) void scatter_sb(
    const int* __restrict__ src, const int* __restrict__ dst,
    int* __restrict__ gc, unsigned* __restrict__ staging,
    int* __restrict__ ocnt, unsigned* __restrict__ ostage, int e) {
  __shared__ unsigned bins[NSB][BINCAP];
  __shared__ int bcount[NSB];
  const int tid  = threadIdx.x;
  const int wv   = tid >> 6;
  const int lane = tid & 63;
  const int sl   = blockIdx.x & (NSUBL - 1);
  for (int i = tid; i < NSB; i += 256) bcount[i] = 0;
  __syncthreads();

  int base = blockIdx.x * EPB;
  int bend = min(base + EPB, e);
  for (int i = base + tid; i < bend; i += 256) {
    int d = dst[i], s = src[i];
    int sb = d >> SBSH;
    int pos = atomicAdd(&bcount[sb], 1);
    if (pos < BINCAP) {
      bins[sb][pos] = (unsigned)s | ((unsigned)(d & 511) << 16);
    } else {
      int op = atomicAdd(ocnt, 1);
      ostage[op] = (unsigned)s | ((unsigned)d << 16);   // full dst
    }
  }
  __syncthreads();

  for (int sb = wv; sb < NSB; sb += 4) {
    int cnt = min(bcount[sb], BINCAP);
    if (cnt > 0) {
      int cell = sb * NSUBL + sl;
      int gbase = 0;
      if (lane == 0) gbase = atomicAdd(&gc[cell * BSTR], cnt);
      gbase = __shfl(gbase, 0);
      if (gbase + cnt <= SUBCAP) {
        if (lane < cnt)
          staging[(size_t)cell * SUBCAP + gbase + lane] = bins[sb][lane];
      } else if (lane < cnt) {
        unsigned u = bins[sb][lane];
        int op = atomicAdd(ocnt, 1);
        ostage[op] = (u & 0xFFFFu) | ((unsigned)((sb << SBSH) | (u >> 16)) << 16);
      }
    }
  }
}

// ---------------------------------------------------------------------------
// 2b) per-SB LDS histogram over the 8 sub-lists -> deg + SB total
__global__ __launch_bounds__(256) void hist_sb(
    const unsigned* __restrict__ staging, const int* __restrict__ gc,
    int* __restrict__ deg, int* __restrict__ sbsum, int n) {
  __shared__ int h[512];
  __shared__ int wt[4];
  int sb = blockIdx.x;
  for (int i = threadIdx.x; i < 512; i += 256) h[i] = 0;
  __syncthreads();
  for (int s = 0; s < NSUBL; ++s) {
    int cell = sb * NSUBL + s;
    int m = min(gc[cell * BSTR], SUBCAP);
    for (int i = threadIdx.x; i < m; i += 256)
      atomicAdd(&h[(staging[(size_t)cell * SUBCAP + i] >> 16) & 511], 1);
  }
  __syncthreads();
  int d0 = sb << SBSH;
  for (int i = threadIdx.x; i < 512; i += 256)
    if (d0 + i < n) deg[d0 + i] = h[i];
  int t = h[threadIdx.x] + h[threadIdx.x + 256];
  #pragma unroll
  for (int off = 32; off; off >>= 1) t += __shfl_xor(t, off);
  if ((threadIdx.x & 63) == 0) wt[threadIdx.x >> 6] = t;
  __syncthreads();
  if (threadIdx.x == 0) sbsum[sb] = wt[0] + wt[1] + wt[2] + wt[3];
}

// ---------------------------------------------------------------------------
// 2b') overflow patch (no-op when ocnt==0)
__global__ __launch_bounds__(256) void overflow_deg(
    const unsigned* __restrict__ ostage, const int* __restrict__ ocnt,
    int* __restrict__ deg, int* __restrict__ sbsum) {
  int m = *ocnt;
  for (int i = blockIdx.x * blockDim.x + threadIdx.x; i < m;
       i += gridDim.x * blockDim.x) {
    int d = (int)(ostage[i] >> 16);
    atomicAdd(&deg[d], 1);
    atomicAdd(&sbsum[d >> SBSH], 1);
  }
}

// ---------------------------------------------------------------------------
// 3a) exclusive scan over the 98 SB sums
__global__ void scan_sb(const int* __restrict__ sbsum, int* __restrict__ sbbase,
                        int* __restrict__ rowptr, int n) {
  __shared__ int part[128];
  int t = (int)threadIdx.x;
  int v = (t < NSB) ? sbsum[t] : 0;
  part[t] = v;
  __syncthreads();
  for (int off = 1; off < 128; off <<= 1) {
    int u = (t >= off) ? part[t - off] : 0;
    __syncthreads();
    part[t] += u;
    __syncthreads();
  }
  if (t < NSB) sbbase[t] = part[t] - v;
  if (t == 127) rowptr[n] = part[127];
}

// ---------------------------------------------------------------------------
// 3b) rowptr within SB: 512-element block scan (2 per thread)
__global__ __launch_bounds__(256) void rowptr_sb(
    const int* __restrict__ deg, const int* __restrict__ sbbase,
    int* __restrict__ rowptr, int n) {
  __shared__ int part[256];
  int sb = blockIdx.x;
  int d0 = sb << SBSH;
  int t = (int)threadIdx.x;
  int e0 = d0 + 2 * t;
  int v0 = (e0 < n) ? deg[e0] : 0;
  int v1 = (e0 + 1 < n) ? deg[e0 + 1] : 0;
  int s = v0 + v1;
  part[t] = s;
  __syncthreads();
  for (int off = 1; off < 256; off <<= 1) {
    int u = (t >= off) ? part[t - off] : 0;
    __syncthreads();
    part[t] += u;
    __syncthreads();
  }
  int ex = part[t] - s + sbbase[sb];
  if (e0 < n) rowptr[e0] = ex;
  if (e0 + 1 < n) rowptr[e0 + 1] = ex + v0;
}

// ---------------------------------------------------------------------------
// 2c) placement (unchanged)
__global__ __launch_bounds__(256) void place_sb(
    const unsigned* __restrict__ staging, const int* __restrict__ gc,
    const int* __restrict__ rowptr, unsigned short* __restrict__ csr16,
    int* __restrict__ gcur, int n) {
  __shared__ int cur[512];
  int sb = blockIdx.x;
  int d0 = sb << SBSH;
  for (int i = threadIdx.x; i < 512; i += 256)
    cur[i] = (d0 + i < n) ? rowptr[d0 + i] : 0;
  __syncthreads();
  for (int s = 0; s < NSUBL; ++s) {
    int cell = sb * NSUBL + s;
    int m = min(gc[cell * BSTR], SUBCAP);
    for (int i = threadIdx.x; i < m; i += 256) {
      unsigned u = staging[(size_t)cell * SUBCAP + i];
      int j = (u >> 16) & 511;
      int pos = atomicAdd(&cur[j], 1);
      csr16[pos] = (unsigned short)(u & 0xFFFFu);
    }
  }
  __syncthreads();
  for (int i = threadIdx.x; i < 512; i += 256)
    if (d0 + i < n) gcur[d0 + i] = cur[i];
}

// ---------------------------------------------------------------------------
// 2c') overflow placement (no-op when ocnt==0)
__global__ __launch_bounds__(256) void overflow_place(
    const unsigned* __restrict__ ostage, const int* __restrict__ ocnt,
    int* __restrict__ gcur, unsigned short* __restrict__ csr16) {
  int m = *ocnt;
  for (int i = blockIdx.x * blockDim.x + threadIdx.x; i < m;
       i += gridDim.x * blockDim.x) {
    unsigned u = ostage[i];
    int d = (int)(u >> 16);
    int pos = atomicAdd(&gcur[d], 1);
    csr16[pos] = (unsigned short)(u & 0xFFFFu);
  }
}

// ---------------------------------------------------------------------------
// 4) FUSED edge-weights + layer-0 aggregation: one 1.6M-edge sweep gathers
// xn8[src] (dot -> w) AND Y8[src] (w-weighted accumulate). Writes csrp +
// denom for layers 1/2; normalizes with locally-computed wsum.
__global__ __launch_bounds__(256) void fused_ew_agg0(
    const unsigned char* __restrict__ xn8, const unsigned char* __restrict__ Y8,
    const __half* __restrict__ Zb, const int* __restrict__ rowptr,
    const unsigned short* __restrict__ csr_src16,
    unsigned* __restrict__ csrp, float* __restrict__ denom,
    const float* __restrict__ g, const float* __restrict__ bb,
    const float* __restrict__ mm, const float* __restrict__ vv,
    __half* __restrict__ outv, int n) {
  int wid  = (int)((blockIdx.x * blockDim.x + threadIdx.x) >> 6);
  int lane = threadIdx.x & 63;
  if (wid >= n) return;
  int grp = lane >> 3;     // edge slot 0..7
  int sub = lane & 7;      // 16-byte slice 0..7
  int beg = rowptr[wid], end = rowptr[wid + 1];
  int4 xdv = ((const int4*)(xn8 + (size_t)wid * 128))[sub];
  float wsum = 0.0f;

  f32x2 a2[8];
  #pragma unroll
  for (int k = 0; k < 8; ++k) a2[k] = (f32x2){0.f, 0.f};

  for (int base = beg; base < end; base += 64) {
    int m = min(64, end - base);
    int sv = (lane < m) ? (int)csr_src16[base + lane] : 0;
    int iters = (m + 7) >> 3;
    #pragma unroll 2
    for (int q = 0; q < iters; ++q) {
      int ei = q * 8 + grp;
      int s = __shfl(sv, ei);
      // similarity dot (xn8 gather)
      int4 xsv = ((const int4*)(xn8 + (size_t)s * 128))[sub];
      float dp = dot16_fp8(xsv, xdv);
      dp += __shfl_xor(dp, 1);
      dp += __shfl_xor(dp, 2);
      dp += __shfl_xor(dp, 4);
      bool valid = ei < m;
      float w = valid ? __expf(dp * (1.0f / TAU)) : 0.0f;
      wsum += w;
      if (valid && sub == 0) {
        unsigned w16 = (unsigned)__half_as_ushort(__float2half_rn(w));
        csrp[base + ei] = (unsigned)s | (w16 << 16);
      }
      // weighted Y accumulate (Y8 gather); w=0 when invalid
      int4 raw = ((const int4*)(Y8 + (size_t)s * 128))[sub];
      unsigned ww[4] = {(unsigned)raw.x, (unsigned)raw.y,
                        (unsigned)raw.z, (unsigned)raw.w};
      f32x2 w2 = {w, w};
      #pragma unroll
      for (int wi = 0; wi < 4; ++wi) {
        f32x2 lo = __builtin_amdgcn_cvt_pk_f32_fp8(ww[wi], false);
        f32x2 hi = __builtin_amdgcn_cvt_pk_f32_fp8(ww[wi], true);
        a2[wi * 2 + 0] = pk_fma(w2, lo, a2[wi * 2 + 0]);
        a2[wi * 2 + 1] = pk_fma(w2, hi, a2[wi * 2 + 1]);
      }
    }
  }
  // wsum: uniform within each 8-lane group; combine the 8 groups
  wsum += __shfl_xor(wsum, 8);
  wsum += __shfl_xor(wsum, 16);
  wsum += __shfl_xor(wsum, 32);
  if (lane == 0) denom[wid] = wsum;
  float inv = 1.0f / (wsum + 1e-16f);

  #pragma unroll
  for (int off = 8; off <= 32; off <<= 1) {
    #pragma unroll
    for (int k = 0; k < 8; ++k) {
      a2[k][0] += __shfl_xor(a2[k][0], off);
      a2[k][1] += __shfl_xor(a2[k][1], off);
    }
  }

  if (lane < 8) {
    int c = sub * 16;
    float o[16];
    const int4* zp = (const int4*)(Zb + (size_t)wid * 128 + c);
    #pragma unroll
    for (int v = 0; v < 2; ++v) {
      int4 zr = zp[v];
      const __half2* zh = (const __half2*)&zr;
      #pragma unroll
      for (int k = 0; k < 4; ++k) {
        float2 z = __half22float2(zh[k]);
        o[v * 8 + 2 * k]     = fmaf(a2[v * 4 + k][0], inv, z.x);
        o[v * 8 + 2 * k + 1] = fmaf(a2[v * 4 + k][1], inv, z.y);
      }
    }
    #pragma unroll
    for (int k = 0; k < 16; ++k) {
      float sc = g[c + k] * rsqrtf(vv[c + k] + BN_EPS);
      o[k] = fmaxf(fmaf(o[k] - mm[c + k], sc, bb[c + k]), 0.0f);
    }
    #pragma unroll
    for (int v = 0; v < 2; ++v) {
      __half2 p0 = __floats2half2_rn(o[v * 8 + 0], o[v * 8 + 1]);
      __half2 p1 = __floats2half2_rn(o[v * 8 + 2], o[v * 8 + 3]);
      __half2 p2 = __floats2half2_rn(o[v * 8 + 4], o[v * 8 + 5]);
      __half2 p3 = __floats2half2_rn(o[v * 8 + 6], o[v * 8 + 7]);
      int4 pk4;
      pk4.x = *(int*)&p0; pk4.y = *(int*)&p1;
      pk4.z = *(int*)&p2; pk4.w = *(int*)&p3;
      ((int4*)(outv + (size_t)wid * 128 + c))[v] = pk4;
    }
  }
}

// ---------------------------------------------------------------------------
// 5a) weight prepack in MFMA fragment order (unchanged)
__global__ __launch_bounds__(256) void prep_weights(
    const float* __restrict__ Wn0, const float* __restrict__ Wr0,
    const float* __restrict__ Wn1, const float* __restrict__ Wr1,
    const float* __restrict__ Wn2, const float* __restrict__ Wr2,
    const float* __restrict__ cn0, const float* __restrict__ cr0,
    const float* __restrict__ cn1, const float* __restrict__ cr1,
    const float* __restrict__ cn2, const float* __restrict__ cr2,
    __half* __restrict__ WtN0, __half* __restrict__ WtR0,
    __half* __restrict__ WtN1, __half* __restrict__ WtR1,
    __half* __restrict__ WtN2, __half* __restrict__ WtR2,
    float* __restrict__ bias0, float* __restrict__ bias1,
    float* __restrict__ bias2) {
  int i = blockIdx.x * blockDim.x + threadIdx.x;
  const float* Ws[6] = {Wn0, Wr0, Wn1, Wr1, Wn2, Wr2};
  __half*     Wts[6] = {WtN0, WtR0, WtN1, WtR1, WtN2, WtR2};
  int seg = -1, off = 0;
  if (i < 65536)        { seg = i >> 14;               off = i & 16383; }
  else if (i < 81920)   { int j = i - 65536; seg = 4 + (j >> 13); off = j & 8191; }
  if (seg >= 0) {
    int DO = (seg < 4) ? 128 : 64;
    int c = off >> 7, k = off & 127;
    int t = c >> 4, kc = k >> 5, kgrp = (k >> 3) & 3, j = k & 7;
    int lane = (c & 15) | (kgrp << 4);
    int idx = (((t * 4 + kc) * 64 + lane) << 3) + j;
    Wts[seg][idx] = __float2half_rn(Ws[seg][(size_t)k * DO + c]);
  }
  if (i < 128) { bias0[i] = cn0[i] + cr0[i]; bias1[i] = cn1[i] + cr1[i]; }
  if (i < 64)  { bias2[i] = cn2[i] + cr2[i]; }
}

// ---------------------------------------------------------------------------
// 5b) dual MFMA GEMM (unchanged)
template <int DO, typename TIN, int YMODE>
__global__ __launch_bounds__(256) void gemm_dual_mfma(
    const TIN* __restrict__ H, const __half* __restrict__ WfN,
    const __half* __restrict__ WfR, const float* __restrict__ bias,
    void* __restrict__ Yv, __half* __restrict__ Z, int n) {
  constexpr int NT = DO / 16;
  const int lane  = threadIdx.x & 63;
  const int w     = threadIdx.x >> 6;
  const int row0  = blockIdx.x * 64 + w * 16;
  const int col16 = lane & 15;
  const int kgrp  = (lane >> 4) * 8;
  const size_t arow = (size_t)min(row0 + col16, n - 1);

  f32x4 acc[2][NT];
  #pragma unroll
  for (int m = 0; m < 2; ++m)
    #pragma unroll
    for (int t = 0; t < NT; ++t) acc[m][t] = (f32x4){0.f, 0.f, 0.f, 0.f};

  #pragma unroll
  for (int kc = 0; kc < 4; ++kc) {
    f16x8 a;
    if constexpr (std::is_same<TIN, float>::value) {
      const float* hp = H + arow * 128 + kc * 32 + kgrp;
      float4 f0 = *(const float4*)hp;
      float4 f1 = *(const float4*)(hp + 4);
      a[0] = (_Float16)f0.x; a[1] = (_Float16)f0.y;
      a[2] = (_Float16)f0.z; a[3] = (_Float16)f0.w;
      a[4] = (_Float16)f1.x; a[5] = (_Float16)f1.y;
      a[6] = (_Float16)f1.z; a[7] = (_Float16)f1.w;
    } else {
      a = *(const f16x8*)(H + arow * 128 + kc * 32 + kgrp);
    }
    const f16x8* bN = (const f16x8*)(WfN + ((size_t)(kc * 64 + lane) << 3));
    const f16x8* bR = (const f16x8*)(WfR + ((size_t)(kc * 64 + lane) << 3));
    #pragma unroll
    for (int t = 0; t < NT; ++t) {
      f16x8 b = bN[t * 256];
      acc[0][t] = __builtin_amdgcn_mfma_f32_16x16x32_f16(a, b, acc[0][t], 0, 0, 0);
    }
    #pragma unroll
    for (int t = 0; t < NT; ++t) {
      f16x8 b = bR[t * 256];
      acc[1][t] = __builtin_amdgcn_mfma_f32_16x16x32_f16(a, b, acc[1][t], 0, 0, 0);
    }
  }

  const int rbase = (lane >> 4) * 4;
  #pragma unroll
  for (int t = 0; t < NT; ++t) {
    int col = t * 16 + col16;
    float bz = bias[col];
    #pragma unroll
    for (int j = 0; j < 4; ++j) {
      int row = row0 + rbase + j;
      if (row < n) {
        if constexpr (YMODE == 1) {
          __hip_fp8_e4m3 q(acc[0][t][j]);
          ((unsigned char*)Yv)[(size_t)row * DO + col] = q.__x;
        } else {
          ((__half*)Yv)[(size_t)row * DO + col] = __float2half_rn(acc[0][t][j]);
        }
        Z[(size_t)row * DO + col] = __float2half_rn(acc[1][t][j] + bz);
      }
    }
  }
}

// ---------------------------------------------------------------------------
// 6) SINGLE-PASS aggregation per layer over contiguous Y rows (layers 1/2;
// unchanged from R22).
template <bool DO_BN, bool HALF_OUT, bool FP8Y>
__global__ __launch_bounds__(256) void agg_pass(
    const void* __restrict__ Ypv, const __half* __restrict__ Zb,
    const int* __restrict__ rowptr, const unsigned* __restrict__ csrp,
    const float* __restrict__ denom,
    const float* __restrict__ g, const float* __restrict__ bb,
    const float* __restrict__ mm, const float* __restrict__ vv,
    void* __restrict__ outv, int dofull, int n) {
  constexpr int CH  = FP8Y ? 16 : 8;   // channels per lane
  constexpr int CH2 = CH / 2;          // f32x2 accumulators
  int wid  = (int)((blockIdx.x * blockDim.x + threadIdx.x) >> 6);
  int lane = threadIdx.x & 63;
  if (wid >= n) return;
  int grp = lane >> 3;     // edge slot 0..7
  int sub = lane & 7;      // channel slice 0..7
  int beg = rowptr[wid], end = rowptr[wid + 1];
  float inv = 1.0f / (denom[wid] + 1e-16f);

  f32x2 a2[CH2];
  #pragma unroll
  for (int k = 0; k < CH2; ++k) a2[k] = (f32x2){0.f, 0.f};

  for (int base = beg; base < end; base += 64) {
    int m = min(64, end - base);
    unsigned pk = (lane < m) ? csrp[base + lane] : 0u;   // w=0 when inactive
    int iters = (m + 7) >> 3;
    #pragma unroll 4
    for (int q = 0; q < iters; ++q) {
      unsigned u = __shfl(pk, q * 8 + grp);
      int   s = (int)(u & 0xFFFFu);
      float w = __half2float(__ushort_as_half((unsigned short)(u >> 16)));
      f32x2 w2 = {w, w};
      if constexpr (FP8Y) {
        int4 raw = ((const int4*)((const unsigned char*)Ypv +
                                  (size_t)s * 128))[sub];
        unsigned ww[4] = {(unsigned)raw.x, (unsigned)raw.y,
                          (unsigned)raw.z, (unsigned)raw.w};
        #pragma unroll
        for (int wi = 0; wi < 4; ++wi) {
          f32x2 lo = __builtin_amdgcn_cvt_pk_f32_fp8(ww[wi], false);
          f32x2 hi = __builtin_amdgcn_cvt_pk_f32_fp8(ww[wi], true);
          a2[wi * 2 + 0] = pk_fma(w2, lo, a2[wi * 2 + 0]);
          a2[wi * 2 + 1] = pk_fma(w2, hi, a2[wi * 2 + 1]);
        }
      } else {
        int4 raw = ((const int4*)((const __half*)Ypv + (size_t)s * 64))[sub];
        const __half2* hh = (const __half2*)&raw;
        #pragma unroll
        for (int k = 0; k < 4; ++k) {
          float2 f = __half22float2(hh[k]);
          f32x2 fv = {f.x, f.y};
          a2[k] = pk_fma(w2, fv, a2[k]);
        }
      }
    }
  }
  #pragma unroll
  for (int off = 8; off <= 32; off <<= 1) {
    #pragma unroll
    for (int k = 0; k < CH2; ++k) {
      a2[k][0] += __shfl_xor(a2[k][0], off);
      a2[k][1] += __shfl_xor(a2[k][1], off);
    }
  }

  if (lane < 8) {
    int c = sub * CH;
    float o[CH];
    const int4* zp = (const int4*)(Zb + (size_t)wid * dofull + c);
    #pragma unroll
    for (int v = 0; v < CH / 8; ++v) {
      int4 zr = zp[v];
      const __half2* zh = (const __half2*)&zr;
      #pragma unroll
      for (int k = 0; k < 4; ++k) {
        float2 z = __half22float2(zh[k]);
        o[v * 8 + 2 * k]     = fmaf(a2[v * 4 + k][0], inv, z.x);
        o[v * 8 + 2 * k + 1] = fmaf(a2[v * 4 + k][1], inv, z.y);
      }
    }
    if constexpr (DO_BN) {
      #pragma unroll
      for (int k = 0; k < CH; ++k) {
        float sc = g[c + k] * rsqrtf(vv[c + k] + BN_EPS);
        o[k] = fmaxf(fmaf(o[k] - mm[c + k], sc, bb[c + k]), 0.0f);
      }
    }
    if constexpr (HALF_OUT) {
      #pragma unroll
      for (int v = 0; v < CH / 8; ++v) {
        __half2 p0 = __floats2half2_rn(o[v * 8 + 0], o[v * 8 + 1]);
        __half2 p1 = __floats2half2_rn(o[v * 8 + 2], o[v * 8 + 3]);
        __half2 p2 = __floats2half2_rn(o[v * 8 + 4], o[v * 8 + 5]);
        __half2 p3 = __floats2half2_rn(o[v * 8 + 6], o[v * 8 + 7]);
        int4 pk4;
        pk4.x = *(int*)&p0; pk4.y = *(int*)&p1;
        pk4.z = *(int*)&p2; pk4.w = *(int*)&p3;
        ((int4*)((__half*)outv + (size_t)wid * dofull + c))[v] = pk4;
      }
    } else {
      float* op = (float*)outv + (size_t)wid * dofull + c;
      #pragma unroll
      for (int v = 0; v < CH / 4; ++v)
        ((float4*)op)[v] = make_float4(o[v * 4], o[v * 4 + 1],
                                       o[v * 4 + 2], o[v * 4 + 3]);
    }
  }
}

// ---------------------------------------------------------------------------
extern "C" void kernel_launch(void* const* d_in, const int* in_sizes, int n_in,
                              void* d_out, int out_size, void* d_ws, size_t ws_size,
                              hipStream_t stream) {
  const float* x   = (const float*)d_in[0];
  const int*   ei  = (const int*)d_in[1];
  const float* Wn0 = (const float*)d_in[2];
  const float* cn0 = (const float*)d_in[3];
  const float* Wr0 = (const float*)d_in[4];
  const float* cr0 = (const float*)d_in[5];
  const float* Wn1 = (const float*)d_in[6];
  const float* cn1 = (const float*)d_in[7];
  const float* Wr1 = (const float*)d_in[8];
  const float* cr1 = (const float*)d_in[9];
  const float* Wn2 = (const float*)d_in[10];
  const float* cn2 = (const float*)d_in[11];
  const float* Wr2 = (const float*)d_in[12];
  const float* cr2 = (const float*)d_in[13];
  const float* g0  = (const float*)d_in[14];
  const float* b0  = (const float*)d_in[15];
  const float* m0  = (const float*)d_in[16];
  const float* v0  = (const float*)d_in[17];
  const float* g1  = (const float*)d_in[18];
  const float* b1  = (const float*)d_in[19];
  const float* m1  = (const float*)d_in[20];
  const float* v1  = (const float*)d_in[21];

  const int* src = ei;
  const int* dst = ei + E_EDGES;

  char* p = (char*)d_ws;
  auto alloc = [&](size_t bytes) {
    char* r = p;
    p += (bytes + 255) & ~(size_t)255;
    return r;
  };
  __half*         P0      = (__half*)        alloc((size_t)N_NODES * 128 * 2);
  __half*         P1      = (__half*)        alloc((size_t)N_NODES * 128 * 2);
  __half*         A16     = (__half*)        alloc((size_t)N_NODES * 128 * 2);
  unsigned*       staging = (unsigned*)      alloc((size_t)NSB * NSUBL * SUBCAP * 4); // 8 MB
  int*            deg     = (int*)           alloc((size_t)N_NODES * 4);
  float*          denom   = (float*)         alloc((size_t)N_NODES * 4);
  int*            rowptr  = (int*)           alloc((size_t)(N_NODES + 1) * 4);
  int*            gcur    = (int*)           alloc((size_t)N_NODES * 4);
  int*            sbsum   = (int*)           alloc((size_t)NSB * 4);
  int*            sbbase  = (int*)           alloc((size_t)NSB * 4);
  int*            gc      = (int*)           alloc((size_t)(NSB * NSUBL * BSTR + 16) * 4);
  unsigned short* csrs16  = (unsigned short*)alloc((size_t)E_EDGES * 2);
  unsigned*       csrp    = (unsigned*)      alloc((size_t)E_EDGES * 4);
  __half*         WtN0    = (__half*)        alloc(128 * 128 * 2);
  __half*         WtR0    = (__half*)        alloc(128 * 128 * 2);
  __half*         WtN1    = (__half*)        alloc(128 * 128 * 2);
  __half*         WtR1    = (__half*)        alloc(128 * 128 * 2);
  __half*         WtN2    = (__half*)        alloc(64 * 128 * 2);
  __half*         WtR2    = (__half*)        alloc(64 * 128 * 2);
  float*          bias0   = (float*)         alloc(128 * 4);
  float*          bias1   = (float*)         alloc(128 * 4);
  float*          bias2   = (float*)         alloc(64 * 4);

  // xn8 lives in P0 and must survive through fused agg0. Y8 (fp8 rows,
  // 6.4 MB) lives in the staging region (dead after place/overflow_place).
  // Final-layer fp16 Y rows reuse P0 (xn8 dead after fused agg0).
  unsigned char* xn8 = (unsigned char*)P0;
  unsigned char* Y8  = (unsigned char*)staging;
  __half*        Yf  = P0;

  // overflow list aliases csrp (csrp only written later by fused agg0)
  unsigned* ostage = (unsigned*)csrp;
  int*      ocnt   = gc + NSB * NSUBL * BSTR;   // covered by gc memset

  hipMemsetAsync(gc, 0, (size_t)(NSB * NSUBL * BSTR + 16) * 4, stream);

  const int node_grid = (N_NODES * 64 + 255) / 256;

  xn_norm<<<node_grid, 256, 0, stream>>>(x, xn8, N_NODES);
  prep_weights<<<320, 256, 0, stream>>>(Wn0, Wr0, Wn1, Wr1, Wn2, Wr2,
                                        cn0, cr0, cn1, cr1, cn2, cr2,
                                        WtN0, WtR0, WtN1, WtR1, WtN2, WtR2,
                                        bias0, bias1, bias2);
  scatter_sb<<<SCGRID, 256, 0, stream>>>(src, dst, gc, staging, ocnt, ostage, E_EDGES);
  hist_sb<<<NSB, 256, 0, stream>>>(staging, gc, deg, sbsum, N_NODES);
  overflow_deg<<<64, 256, 0, stream>>>(ostage, ocnt, deg, sbsum);
  scan_sb<<<1, 128, 0, stream>>>(sbsum, sbbase, rowptr, N_NODES);
  rowptr_sb<<<NSB, 256, 0, stream>>>(deg, sbbase, rowptr, N_NODES);
  place_sb<<<NSB, 256, 0, stream>>>(staging, gc, rowptr, csrs16, gcur, N_NODES);
  overflow_place<<<64, 256, 0, stream>>>(ostage, ocnt, gcur, csrs16);

  const int gemm_grid = (N_NODES + 63) / 64;

  // layer 0: gemm (Y8 -> staging region, which is now dead), then FUSED
  // edge-weights + aggregation (writes csrp, denom, A16).
  gemm_dual_mfma<128, float, 1><<<gemm_grid, 256, 0, stream>>>(
      x, WtN0, WtR0, bias0, Y8, P1, N_NODES);
  fused_ew_agg0<<<node_grid, 256, 0, stream>>>(
      xn8, Y8, P1, rowptr, csrs16, csrp, denom,
      g0, b0, m0, v0, A16, N_NODES);

  // layer 1: H = A16 (fp16)
  gemm_dual_mfma<128, __half, 1><<<gemm_grid, 256, 0, stream>>>(
      A16, WtN1, WtR1, bias1, Y8, P1, N_NODES);
  agg_pass<true, true, true><<<node_grid, 256, 0, stream>>>(
      Y8, P1, rowptr, csrp, denom, g1, b1, m1, v1, A16, 128, N_NODES);

  // layer 2 (64-wide): Y -> fp16 64-ch rows in P0 (xn8 dead), out -> d_out
  gemm_dual_mfma<64, __half, 0><<<gemm_grid, 256, 0, stream>>>(
      A16, WtN2, WtR2, bias2, Yf, P1, N_NODES);
  agg_pass<false, false, false><<<node_grid, 256, 0, stream>>>(
      Yf, P1, rowptr, csrp, denom,
      nullptr, nullptr, nullptr, nullptr, d_out, 64, N_NODES);
}

// Round 24
// 335.580 us; speedup vs baseline: 1.8579x; 1.0442x over previous
//
#include <hip/hip_runtime.h>
#include <hip/hip_fp16.h>
#include <hip/hip_fp8.h>
#include <math.h>
#include <type_traits>

#define N_NODES 50000
#define E_EDGES 1600000
#define TAU     0.5f
#define BN_EPS  1e-5f
#define SBSH    9                        // 512 dst nodes per super-bucket
#define NSB     ((N_NODES + 511) >> 9)   // 98 super-buckets
#define NSUBL   8                        // staging sub-lists (spread cursor LINES)
#define SUBCAP  2560                     // entries per sub-list (mean 2048 + >10 sigma)
#define BINCAP  48                       // LDS bin capacity (mean 10.4, +11 sigma)
#define EPB     1024                     // edges per scatter block
#define SCGRID  ((E_EDGES + EPB - 1) / EPB)
#define BSTR    16                       // cursor stride in ints (64B/line)

typedef _Float16 f16x8 __attribute__((ext_vector_type(8)));
typedef float    f32x4 __attribute__((ext_vector_type(4)));
typedef float    f32x2 __attribute__((ext_vector_type(2)));

// packed dual-FMA on f32 pairs (v_pk_fma_f32, gfx90a+): d = a*b + c
__device__ __forceinline__ f32x2 pk_fma(f32x2 a, f32x2 b, f32x2 c) {
  f32x2 d;
  asm volatile("v_pk_fma_f32 %0, %1, %2, %3"
               : "=v"(d) : "v"(a), "v"(b), "v"(c));
  return d;
}

// dot of 16 fp8 pairs held in two int4 registers (OCP e4m3, HW cvt)
__device__ __forceinline__ float dot16_fp8(int4 a, int4 b) {
  unsigned wa[4] = {(unsigned)a.x, (unsigned)a.y, (unsigned)a.z, (unsigned)a.w};
  unsigned wb[4] = {(unsigned)b.x, (unsigned)b.y, (unsigned)b.z, (unsigned)b.w};
  float acc = 0.0f;
  #pragma unroll
  for (int i = 0; i < 4; ++i) {
    f32x2 alo = __builtin_amdgcn_cvt_pk_f32_fp8(wa[i], false);
    f32x2 ahi = __builtin_amdgcn_cvt_pk_f32_fp8(wa[i], true);
    f32x2 blo = __builtin_amdgcn_cvt_pk_f32_fp8(wb[i], false);
    f32x2 bhi = __builtin_amdgcn_cvt_pk_f32_fp8(wb[i], true);
    acc = fmaf(alo[0], blo[0], acc);
    acc = fmaf(alo[1], blo[1], acc);
    acc = fmaf(ahi[0], bhi[0], acc);
    acc = fmaf(ahi[1], bhi[1], acc);
  }
  return acc;
}

// ---------------------------------------------------------------------------
// 1) normalized FP8 features + per-node scale: xn8 = e4m3(x/sc), sc=||x||+eps
__global__ __launch_bounds__(256) void xn_norm(
    const float* __restrict__ x, unsigned char* __restrict__ xn8,
    float* __restrict__ norms, int n) {
  int wid  = (int)((blockIdx.x * blockDim.x + threadIdx.x) >> 6);
  int lane = threadIdx.x & 63;
  if (wid >= n) return;
  float2 v = ((const float2*)(x + (size_t)wid * 128))[lane];
  float s = v.x * v.x + v.y * v.y;
  #pragma unroll
  for (int off = 32; off; off >>= 1) s += __shfl_xor(s, off);
  float sc = sqrtf(s) + 1e-12f;
  float inv = 1.0f / sc;
  __hip_fp8_e4m3 q0(v.x * inv), q1(v.y * inv);
  uchar2 pk;
  pk.x = q0.__x; pk.y = q1.__x;
  ((uchar2*)(xn8 + (size_t)wid * 128))[lane] = pk;
  if (lane == 0) norms[wid] = sc;
}

// ---------------------------------------------------------------------------
// 2a) LDS-binned scatter (unchanged)
__global__ __launch_bounds__(256) void scatter_sb(
    const int* __restrict__ src, const int* __restrict__ dst,
    int* __restrict__ gc, unsigned* __restrict__ staging,
    int* __restrict__ ocnt, unsigned* __restrict__ ostage, int e) {
  __shared__ unsigned bins[NSB][BINCAP];
  __shared__ int bcount[NSB];
  const int tid  = threadIdx.x;
  const int wv   = tid >> 6;
  const int lane = tid & 63;
  const int sl   = blockIdx.x & (NSUBL - 1);
  for (int i = tid; i < NSB; i += 256) bcount[i] = 0;
  __syncthreads();

  int base = blockIdx.x * EPB;
  int bend = min(base + EPB, e);
  for (int i = base + tid; i < bend; i += 256) {
    int d = dst[i], s = src[i];
    int sb = d >> SBSH;
    int pos = atomicAdd(&bcount[sb], 1);
    if (pos < BINCAP) {
      bins[sb][pos] = (unsigned)s | ((unsigned)(d & 511) << 16);
    } else {
      int op = atomicAdd(ocnt, 1);
      ostage[op] = (unsigned)s | ((unsigned)d << 16);   // full dst
    }
  }
  __syncthreads();

  for (int sb = wv; sb < NSB; sb += 4) {
    int cnt = min(bcount[sb], BINCAP);
    if (cnt > 0) {
      int cell = sb * NSUBL + sl;
      int gbase = 0;
      if (lane == 0) gbase = atomicAdd(&gc[cell * BSTR], cnt);
      gbase = __shfl(gbase, 0);
      if (gbase + cnt <= SUBCAP) {
        if (lane < cnt)
          staging[(size_t)cell * SUBCAP + gbase + lane] = bins[sb][lane];
      } else if (lane < cnt) {
        unsigned u = bins[sb][lane];
        int op = atomicAdd(ocnt, 1);
        ostage[op] = (u & 0xFFFFu) | ((unsigned)((sb << SBSH) | (u >> 16)) << 16);
      }
    }
  }
}

// ---------------------------------------------------------------------------
// 2b) per-SB LDS histogram -> deg + SB total
__global__ __launch_bounds__(256) void hist_sb(
    const unsigned* __restrict__ staging, const int* __restrict__ gc,
    int* __restrict__ deg, int* __restrict__ sbsum, int n) {
  __shared__ int h[512];
  __shared__ int wt[4];
  int sb = blockIdx.x;
  for (int i = threadIdx.x; i < 512; i += 256) h[i] = 0;
  __syncthreads();
  for (int s = 0; s < NSUBL; ++s) {
    int cell = sb * NSUBL + s;
    int m = min(gc[cell * BSTR], SUBCAP);
    for (int i = threadIdx.x; i < m; i += 256)
      atomicAdd(&h[(staging[(size_t)cell * SUBCAP + i] >> 16) & 511], 1);
  }
  __syncthreads();
  int d0 = sb << SBSH;
  for (int i = threadIdx.x; i < 512; i += 256)
    if (d0 + i < n) deg[d0 + i] = h[i];
  int t = h[threadIdx.x] + h[threadIdx.x + 256];
  #pragma unroll
  for (int off = 32; off; off >>= 1) t += __shfl_xor(t, off);
  if ((threadIdx.x & 63) == 0) wt[threadIdx.x >> 6] = t;
  __syncthreads();
  if (threadIdx.x == 0) sbsum[sb] = wt[0] + wt[1] + wt[2] + wt[3];
}

// ---------------------------------------------------------------------------
// 2b') overflow patch (no-op when ocnt==0)
__global__ __launch_bounds__(256) void overflow_deg(
    const unsigned* __restrict__ ostage, const int* __restrict__ ocnt,
    int* __restrict__ deg, int* __restrict__ sbsum) {
  int m = *ocnt;
  for (int i = blockIdx.x * blockDim.x + threadIdx.x; i < m;
       i += gridDim.x * blockDim.x) {
    int d = (int)(ostage[i] >> 16);
    atomicAdd(&deg[d], 1);
    atomicAdd(&sbsum[d >> SBSH], 1);
  }
}

// ---------------------------------------------------------------------------
// 3a) exclusive scan over the 98 SB sums
__global__ void scan_sb(const int* __restrict__ sbsum, int* __restrict__ sbbase,
                        int* __restrict__ rowptr, int n) {
  __shared__ int part[128];
  int t = (int)threadIdx.x;
  int v = (t < NSB) ? sbsum[t] : 0;
  part[t] = v;
  __syncthreads();
  for (int off = 1; off < 128; off <<= 1) {
    int u = (t >= off) ? part[t - off] : 0;
    __syncthreads();
    part[t] += u;
    __syncthreads();
  }
  if (t < NSB) sbbase[t] = part[t] - v;
  if (t == 127) rowptr[n] = part[127];
}

// ---------------------------------------------------------------------------
// 3b) rowptr within SB
__global__ __launch_bounds__(256) void rowptr_sb(
    const int* __restrict__ deg, const int* __restrict__ sbbase,
    int* __restrict__ rowptr, int n) {
  __shared__ int part[256];
  int sb = blockIdx.x;
  int d0 = sb << SBSH;
  int t = (int)threadIdx.x;
  int e0 = d0 + 2 * t;
  int v0 = (e0 < n) ? deg[e0] : 0;
  int v1 = (e0 + 1 < n) ? deg[e0 + 1] : 0;
  int s = v0 + v1;
  part[t] = s;
  __syncthreads();
  for (int off = 1; off < 256; off <<= 1) {
    int u = (t >= off) ? part[t - off] : 0;
    __syncthreads();
    part[t] += u;
    __syncthreads();
  }
  int ex = part[t] - s + sbbase[sb];
  if (e0 < n) rowptr[e0] = ex;
  if (e0 + 1 < n) rowptr[e0 + 1] = ex + v0;
}

// ---------------------------------------------------------------------------
// 2c) placement (unchanged)
__global__ __launch_bounds__(256) void place_sb(
    const unsigned* __restrict__ staging, const int* __restrict__ gc,
    const int* __restrict__ rowptr, unsigned short* __restrict__ csr16,
    int* __restrict__ gcur, int n) {
  __shared__ int cur[512];
  int sb = blockIdx.x;
  int d0 = sb << SBSH;
  for (int i = threadIdx.x; i < 512; i += 256)
    cur[i] = (d0 + i < n) ? rowptr[d0 + i] : 0;
  __syncthreads();
  for (int s = 0; s < NSUBL; ++s) {
    int cell = sb * NSUBL + s;
    int m = min(gc[cell * BSTR], SUBCAP);
    for (int i = threadIdx.x; i < m; i += 256) {
      unsigned u = staging[(size_t)cell * SUBCAP + i];
      int j = (u >> 16) & 511;
      int pos = atomicAdd(&cur[j], 1);
      csr16[pos] = (unsigned short)(u & 0xFFFFu);
    }
  }
  __syncthreads();
  for (int i = threadIdx.x; i < 512; i += 256)
    if (d0 + i < n) gcur[d0 + i] = cur[i];
}

// ---------------------------------------------------------------------------
// 2c') overflow placement (no-op when ocnt==0)
__global__ __launch_bounds__(256) void overflow_place(
    const unsigned* __restrict__ ostage, const int* __restrict__ ocnt,
    int* __restrict__ gcur, unsigned short* __restrict__ csr16) {
  int m = *ocnt;
  for (int i = blockIdx.x * blockDim.x + threadIdx.x; i < m;
       i += gridDim.x * blockDim.x) {
    unsigned u = ostage[i];
    int d = (int)(u >> 16);
    int pos = atomicAdd(&gcur[d], 1);
    csr16[pos] = (unsigned short)(u & 0xFFFFu);
  }
}

// ---------------------------------------------------------------------------
// 4) FUSED edge-weights + layer-0 raw aggregation, SINGLE gather per edge:
// xsv (xn8[src]) serves the similarity dot AND the accumulation of
// sum(w * x[src]) via x[src] = xn8[src] * norms[src]. Writes csrp, denom,
// aggX (fp16, unnormalized). Normalization happens in the gemm epilogue.
__global__ __launch_bounds__(256) void fused_ew_agg0(
    const unsigned char* __restrict__ xn8, const float* __restrict__ norms,
    const int* __restrict__ rowptr, const unsigned short* __restrict__ csr_src16,
    unsigned* __restrict__ csrp, float* __restrict__ denom,
    __half* __restrict__ aggX, int n) {
  int wid  = (int)((blockIdx.x * blockDim.x + threadIdx.x) >> 6);
  int lane = threadIdx.x & 63;
  if (wid >= n) return;
  int grp = lane >> 3;     // edge slot 0..7
  int sub = lane & 7;      // 16-byte slice 0..7
  int beg = rowptr[wid], end = rowptr[wid + 1];
  int4 xdv = ((const int4*)(xn8 + (size_t)wid * 128))[sub];
  float wsum = 0.0f;

  f32x2 a2[8];
  #pragma unroll
  for (int k = 0; k < 8; ++k) a2[k] = (f32x2){0.f, 0.f};

  for (int base = beg; base < end; base += 64) {
    int m = min(64, end - base);
    int sv = (lane < m) ? (int)csr_src16[base + lane] : 0;
    int iters = (m + 7) >> 3;
    #pragma unroll 2
    for (int q = 0; q < iters; ++q) {
      int ei = q * 8 + grp;
      int s = __shfl(sv, ei);
      int4 xsv = ((const int4*)(xn8 + (size_t)s * 128))[sub];   // ONE gather
      float dp = dot16_fp8(xsv, xdv);
      dp += __shfl_xor(dp, 1);
      dp += __shfl_xor(dp, 2);
      dp += __shfl_xor(dp, 4);
      bool valid = ei < m;
      float w = valid ? __expf(dp * (1.0f / TAU)) : 0.0f;
      wsum += w;
      if (valid && sub == 0) {
        unsigned w16 = (unsigned)__half_as_ushort(__float2half_rn(w));
        csrp[base + ei] = (unsigned)s | (w16 << 16);
      }
      float ws = w * norms[s];          // x[src] = xn8[src]*norms[src]
      f32x2 w2 = {ws, ws};
      unsigned ww[4] = {(unsigned)xsv.x, (unsigned)xsv.y,
                        (unsigned)xsv.z, (unsigned)xsv.w};
      #pragma unroll
      for (int wi = 0; wi < 4; ++wi) {
        f32x2 lo = __builtin_amdgcn_cvt_pk_f32_fp8(ww[wi], false);
        f32x2 hi = __builtin_amdgcn_cvt_pk_f32_fp8(ww[wi], true);
        a2[wi * 2 + 0] = pk_fma(w2, lo, a2[wi * 2 + 0]);
        a2[wi * 2 + 1] = pk_fma(w2, hi, a2[wi * 2 + 1]);
      }
    }
  }
  wsum += __shfl_xor(wsum, 8);
  wsum += __shfl_xor(wsum, 16);
  wsum += __shfl_xor(wsum, 32);
  if (lane == 0) denom[wid] = wsum;

  #pragma unroll
  for (int off = 8; off <= 32; off <<= 1) {
    #pragma unroll
    for (int k = 0; k < 8; ++k) {
      a2[k][0] += __shfl_xor(a2[k][0], off);
      a2[k][1] += __shfl_xor(a2[k][1], off);
    }
  }

  if (lane < 8) {
    int c = sub * 16;
    #pragma unroll
    for (int v = 0; v < 2; ++v) {
      __half2 p0 = __floats2half2_rn(a2[v * 4 + 0][0], a2[v * 4 + 0][1]);
      __half2 p1 = __floats2half2_rn(a2[v * 4 + 1][0], a2[v * 4 + 1][1]);
      __half2 p2 = __floats2half2_rn(a2[v * 4 + 2][0], a2[v * 4 + 2][1]);
      __half2 p3 = __floats2half2_rn(a2[v * 4 + 3][0], a2[v * 4 + 3][1]);
      int4 pk4;
      pk4.x = *(int*)&p0; pk4.y = *(int*)&p1;
      pk4.z = *(int*)&p2; pk4.w = *(int*)&p3;
      ((int4*)(aggX + (size_t)wid * 128 + c))[v] = pk4;
    }
  }
}

// ---------------------------------------------------------------------------
// 4b) aggregation of fp8 H rows (layers 1/2): aggH = sum(w * H8[src]),
// fp16 output, unnormalized (gemm epilogue divides).
__global__ __launch_bounds__(256) void agg_h8(
    const unsigned char* __restrict__ H8, const int* __restrict__ rowptr,
    const unsigned* __restrict__ csrp, __half* __restrict__ aggH, int n) {
  int wid  = (int)((blockIdx.x * blockDim.x + threadIdx.x) >> 6);
  int lane = threadIdx.x & 63;
  if (wid >= n) return;
  int grp = lane >> 3;
  int sub = lane & 7;
  int beg = rowptr[wid], end = rowptr[wid + 1];

  f32x2 a2[8];
  #pragma unroll
  for (int k = 0; k < 8; ++k) a2[k] = (f32x2){0.f, 0.f};

  for (int base = beg; base < end; base += 64) {
    int m = min(64, end - base);
    unsigned pk = (lane < m) ? csrp[base + lane] : 0u;
    int iters = (m + 7) >> 3;
    #pragma unroll 4
    for (int q = 0; q < iters; ++q) {
      unsigned u = __shfl(pk, q * 8 + grp);
      int   s = (int)(u & 0xFFFFu);
      float w = __half2float(__ushort_as_half((unsigned short)(u >> 16)));
      f32x2 w2 = {w, w};
      int4 raw = ((const int4*)(H8 + (size_t)s * 128))[sub];
      unsigned ww[4] = {(unsigned)raw.x, (unsigned)raw.y,
                        (unsigned)raw.z, (unsigned)raw.w};
      #pragma unroll
      for (int wi = 0; wi < 4; ++wi) {
        f32x2 lo = __builtin_amdgcn_cvt_pk_f32_fp8(ww[wi], false);
        f32x2 hi = __builtin_amdgcn_cvt_pk_f32_fp8(ww[wi], true);
        a2[wi * 2 + 0] = pk_fma(w2, lo, a2[wi * 2 + 0]);
        a2[wi * 2 + 1] = pk_fma(w2, hi, a2[wi * 2 + 1]);
      }
    }
  }
  #pragma unroll
  for (int off = 8; off <= 32; off <<= 1) {
    #pragma unroll
    for (int k = 0; k < 8; ++k) {
      a2[k][0] += __shfl_xor(a2[k][0], off);
      a2[k][1] += __shfl_xor(a2[k][1], off);
    }
  }

  if (lane < 8) {
    int c = sub * 16;
    #pragma unroll
    for (int v = 0; v < 2; ++v) {
      __half2 p0 = __floats2half2_rn(a2[v * 4 + 0][0], a2[v * 4 + 0][1]);
      __half2 p1 = __floats2half2_rn(a2[v * 4 + 1][0], a2[v * 4 + 1][1]);
      __half2 p2 = __floats2half2_rn(a2[v * 4 + 2][0], a2[v * 4 + 2][1]);
      __half2 p3 = __floats2half2_rn(a2[v * 4 + 3][0], a2[v * 4 + 3][1]);
      int4 pk4;
      pk4.x = *(int*)&p0; pk4.y = *(int*)&p1;
      pk4.z = *(int*)&p2; pk4.w = *(int*)&p3;
      ((int4*)(aggH + (size_t)wid * 128 + c))[v] = pk4;
    }
  }
}

// ---------------------------------------------------------------------------
// 5a) weight prepack in MFMA fragment order (unchanged)
__global__ __launch_bounds__(256) void prep_weights(
    const float* __restrict__ Wn0, const float* __restrict__ Wr0,
    const float* __restrict__ Wn1, const float* __restrict__ Wr1,
    const float* __restrict__ Wn2, const float* __restrict__ Wr2,
    const float* __restrict__ cn0, const float* __restrict__ cr0,
    const float* __restrict__ cn1, const float* __restrict__ cr1,
    const float* __restrict__ cn2, const float* __restrict__ cr2,
    __half* __restrict__ WtN0, __half* __restrict__ WtR0,
    __half* __restrict__ WtN1, __half* __restrict__ WtR1,
    __half* __restrict__ WtN2, __half* __restrict__ WtR2,
    float* __restrict__ bias0, float* __restrict__ bias1,
    float* __restrict__ bias2) {
  int i = blockIdx.x * blockDim.x + threadIdx.x;
  const float* Ws[6] = {Wn0, Wr0, Wn1, Wr1, Wn2, Wr2};
  __half*     Wts[6] = {WtN0, WtR0, WtN1, WtR1, WtN2, WtR2};
  int seg = -1, off = 0;
  if (i < 65536)        { seg = i >> 14;               off = i & 16383; }
  else if (i < 81920)   { int j = i - 65536; seg = 4 + (j >> 13); off = j & 8191; }
  if (seg >= 0) {
    int DO = (seg < 4) ? 128 : 64;
    int c = off >> 7, k = off & 127;
    int t = c >> 4, kc = k >> 5, kgrp = (k >> 3) & 3, j = k & 7;
    int lane = (c & 15) | (kgrp << 4);
    int idx = (((t * 4 + kc) * 64 + lane) << 3) + j;
    Wts[seg][idx] = __float2half_rn(Ws[seg][(size_t)k * DO + c]);
  }
  if (i < 128) { bias0[i] = cn0[i] + cr0[i]; bias1[i] = cn1[i] + cr1[i]; }
  if (i < 64)  { bias2[i] = cn2[i] + cr2[i]; }
}

// ---------------------------------------------------------------------------
// 5b) post-agg dual MFMA GEMM: out = Agg@WfN * inv_denom + H@WfR + bias
// (+BN+ReLU for hidden layers). Hidden: writes H fp16 + H8 fp8; final:
// writes f32 straight to d_out. Z never materialized.
template <int DO, typename TIN1, bool DO_BN>
__global__ __launch_bounds__(256) void gemm_post(
    const __half* __restrict__ Agg, const TIN1* __restrict__ H,
    const __half* __restrict__ WfN, const __half* __restrict__ WfR,
    const float* __restrict__ bias, const float* __restrict__ denom,
    const float* __restrict__ g, const float* __restrict__ bb,
    const float* __restrict__ mm, const float* __restrict__ vv,
    void* __restrict__ outH, unsigned char* __restrict__ outH8, int n) {
  constexpr int NT = DO / 16;
  const int lane  = threadIdx.x & 63;
  const int w     = threadIdx.x >> 6;
  const int row0  = blockIdx.x * 64 + w * 16;
  const int col16 = lane & 15;
  const int kgrp  = (lane >> 4) * 8;
  const size_t arow = (size_t)min(row0 + col16, n - 1);

  f32x4 acc[2][NT];
  #pragma unroll
  for (int m = 0; m < 2; ++m)
    #pragma unroll
    for (int t = 0; t < NT; ++t) acc[m][t] = (f32x4){0.f, 0.f, 0.f, 0.f};

  #pragma unroll
  for (int kc = 0; kc < 4; ++kc) {
    f16x8 a0 = *(const f16x8*)(Agg + arow * 128 + kc * 32 + kgrp);
    f16x8 a1;
    if constexpr (std::is_same<TIN1, float>::value) {
      const float* hp = H + arow * 128 + kc * 32 + kgrp;
      float4 f0 = *(const float4*)hp;
      float4 f1 = *(const float4*)(hp + 4);
      a1[0] = (_Float16)f0.x; a1[1] = (_Float16)f0.y;
      a1[2] = (_Float16)f0.z; a1[3] = (_Float16)f0.w;
      a1[4] = (_Float16)f1.x; a1[5] = (_Float16)f1.y;
      a1[6] = (_Float16)f1.z; a1[7] = (_Float16)f1.w;
    } else {
      a1 = *(const f16x8*)(H + arow * 128 + kc * 32 + kgrp);
    }
    const f16x8* bN = (const f16x8*)(WfN + ((size_t)(kc * 64 + lane) << 3));
    const f16x8* bR = (const f16x8*)(WfR + ((size_t)(kc * 64 + lane) << 3));
    #pragma unroll
    for (int t = 0; t < NT; ++t) {
      f16x8 b = bN[t * 256];
      acc[0][t] = __builtin_amdgcn_mfma_f32_16x16x32_f16(a0, b, acc[0][t], 0, 0, 0);
    }
    #pragma unroll
    for (int t = 0; t < NT; ++t) {
      f16x8 b = bR[t * 256];
      acc[1][t] = __builtin_amdgcn_mfma_f32_16x16x32_f16(a1, b, acc[1][t], 0, 0, 0);
    }
  }

  const int rbase = (lane >> 4) * 4;
  float invd[4];
  #pragma unroll
  for (int j = 0; j < 4; ++j) {
    int row = row0 + rbase + j;
    invd[j] = 1.0f / (denom[min(row, n - 1)] + 1e-16f);
  }

  #pragma unroll
  for (int t = 0; t < NT; ++t) {
    int col = t * 16 + col16;
    float bz = bias[col];
    float sc = 0.f, sm = 0.f, sb2 = 0.f;
    if constexpr (DO_BN) {
      sc = g[col] * rsqrtf(vv[col] + BN_EPS);
      sm = mm[col];
      sb2 = bb[col];
    }
    #pragma unroll
    for (int j = 0; j < 4; ++j) {
      int row = row0 + rbase + j;
      if (row < n) {
        float o = fmaf(acc[0][t][j], invd[j], acc[1][t][j] + bz);
        if constexpr (DO_BN) {
          o = fmaxf(fmaf(o - sm, sc, sb2), 0.0f);
          ((__half*)outH)[(size_t)row * DO + col] = __float2half_rn(o);
          __hip_fp8_e4m3 q(o);
          outH8[(size_t)row * DO + col] = q.__x;
        } else {
          ((float*)outH)[(size_t)row * DO + col] = o;
        }
      }
    }
  }
}

// ---------------------------------------------------------------------------
extern "C" void kernel_launch(void* const* d_in, const int* in_sizes, int n_in,
                              void* d_out, int out_size, void* d_ws, size_t ws_size,
                              hipStream_t stream) {
  const float* x   = (const float*)d_in[0];
  const int*   ei  = (const int*)d_in[1];
  const float* Wn0 = (const float*)d_in[2];
  const float* cn0 = (const float*)d_in[3];
  const float* Wr0 = (const float*)d_in[4];
  const float* cr0 = (const float*)d_in[5];
  const float* Wn1 = (const float*)d_in[6];
  const float* cn1 = (const float*)d_in[7];
  const float* Wr1 = (const float*)d_in[8];
  const float* cr1 = (const float*)d_in[9];
  const float* Wn2 = (const float*)d_in[10];
  const float* cn2 = (const float*)d_in[11];
  const float* Wr2 = (const float*)d_in[12];
  const float* cr2 = (const float*)d_in[13];
  const float* g0  = (const float*)d_in[14];
  const float* b0  = (const float*)d_in[15];
  const float* m0  = (const float*)d_in[16];
  const float* v0  = (const float*)d_in[17];
  const float* g1  = (const float*)d_in[18];
  const float* b1  = (const float*)d_in[19];
  const float* m1  = (const float*)d_in[20];
  const float* v1  = (const float*)d_in[21];

  const int* src = ei;
  const int* dst = ei + E_EDGES;

  char* p = (char*)d_ws;
  auto alloc = [&](size_t bytes) {
    char* r = p;
    p += (bytes + 255) & ~(size_t)255;
    return r;
  };
  __half*         P0      = (__half*)        alloc((size_t)N_NODES * 128 * 2);  // xn8 -> H2
  __half*         P1      = (__half*)        alloc((size_t)N_NODES * 128 * 2);  // aggX/aggH
  __half*         A16     = (__half*)        alloc((size_t)N_NODES * 128 * 2);  // H1
  unsigned*       staging = (unsigned*)      alloc((size_t)NSB * NSUBL * SUBCAP * 4); // 8 MB -> H8
  int*            deg     = (int*)           alloc((size_t)N_NODES * 4);
  float*          denom   = (float*)         alloc((size_t)N_NODES * 4);
  float*          norms   = (float*)         alloc((size_t)N_NODES * 4);
  int*            rowptr  = (int*)           alloc((size_t)(N_NODES + 1) * 4);
  int*            gcur    = (int*)           alloc((size_t)N_NODES * 4);
  int*            sbsum   = (int*)           alloc((size_t)NSB * 4);
  int*            sbbase  = (int*)           alloc((size_t)NSB * 4);
  int*            gc      = (int*)           alloc((size_t)(NSB * NSUBL * BSTR + 16) * 4);
  unsigned short* csrs16  = (unsigned short*)alloc((size_t)E_EDGES * 2);
  unsigned*       csrp    = (unsigned*)      alloc((size_t)E_EDGES * 4);
  __half*         WtN0    = (__half*)        alloc(128 * 128 * 2);
  __half*         WtR0    = (__half*)        alloc(128 * 128 * 2);
  __half*         WtN1    = (__half*)        alloc(128 * 128 * 2);
  __half*         WtR1    = (__half*)        alloc(128 * 128 * 2);
  __half*         WtN2    = (__half*)        alloc(64 * 128 * 2);
  __half*         WtR2    = (__half*)        alloc(64 * 128 * 2);
  float*          bias0   = (float*)         alloc(128 * 4);
  float*          bias1   = (float*)         alloc(128 * 4);
  float*          bias2   = (float*)         alloc(64 * 4);

  // lifetimes: xn8 in P0 (dead after fused) -> H2 fp16 reuses P0.
  // H8 (fp8 6.4 MB, written by gemm0/gemm1) lives in staging (dead after place).
  unsigned char* xn8 = (unsigned char*)P0;
  unsigned char* H8  = (unsigned char*)staging;
  __half*        H2  = P0;

  // overflow list aliases csrp (csrp only written later by fused)
  unsigned* ostage = (unsigned*)csrp;
  int*      ocnt   = gc + NSB * NSUBL * BSTR;   // covered by gc memset

  hipMemsetAsync(gc, 0, (size_t)(NSB * NSUBL * BSTR + 16) * 4, stream);

  const int node_grid = (N_NODES * 64 + 255) / 256;
  const int gemm_grid = (N_NODES + 63) / 64;

  xn_norm<<<node_grid, 256, 0, stream>>>(x, xn8, norms, N_NODES);
  prep_weights<<<320, 256, 0, stream>>>(Wn0, Wr0, Wn1, Wr1, Wn2, Wr2,
                                        cn0, cr0, cn1, cr1, cn2, cr2,
                                        WtN0, WtR0, WtN1, WtR1, WtN2, WtR2,
                                        bias0, bias1, bias2);
  scatter_sb<<<SCGRID, 256, 0, stream>>>(src, dst, gc, staging, ocnt, ostage, E_EDGES);
  hist_sb<<<NSB, 256, 0, stream>>>(staging, gc, deg, sbsum, N_NODES);
  overflow_deg<<<64, 256, 0, stream>>>(ostage, ocnt, deg, sbsum);
  scan_sb<<<1, 128, 0, stream>>>(sbsum, sbbase, rowptr, N_NODES);
  rowptr_sb<<<NSB, 256, 0, stream>>>(deg, sbbase, rowptr, N_NODES);
  place_sb<<<NSB, 256, 0, stream>>>(staging, gc, rowptr, csrs16, gcur, N_NODES);
  overflow_place<<<64, 256, 0, stream>>>(ostage, ocnt, gcur, csrs16);

  // layer 0: fused edge-weight + raw-x aggregation (single gather), then gemm
  fused_ew_agg0<<<node_grid, 256, 0, stream>>>(
      xn8, norms, rowptr, csrs16, csrp, denom, P1, N_NODES);
  gemm_post<128, float, true><<<gemm_grid, 256, 0, stream>>>(
      P1, x, WtN0, WtR0, bias0, denom, g0, b0, m0, v0, A16, H8, N_NODES);

  // layer 1: agg over H1 fp8, then gemm -> H2 (P0; xn8 dead) + H8
  agg_h8<<<node_grid, 256, 0, stream>>>(H8, rowptr, csrp, P1, N_NODES);
  gemm_post<128, __half, true><<<gemm_grid, 256, 0, stream>>>(
      P1, A16, WtN1, WtR1, bias1, denom, g1, b1, m1, v1, H2, H8, N_NODES);

  // layer 2: agg over H2 fp8, then gemm straight to d_out (f32)
  agg_h8<<<node_grid, 256, 0, stream>>>(H8, rowptr, csrp, P1, N_NODES);
  gemm_post<64, __half, false><<<gemm_grid, 256, 0, stream>>>(
      P1, H2, WtN2, WtR2, bias2, denom,
      nullptr, nullptr, nullptr, nullptr, d_out, nullptr, N_NODES);
}